// Round 7
// baseline (438.822 us; speedup 1.0000x reference)
//
#include <hip/hip_runtime.h>
#include <math.h>

typedef unsigned short u16;

constexpr int cB = 2;
constexpr int cS = 1024;
constexpr int cH = 1024;
constexpr int cNH = 16;
constexpr int cHD = 64;
constexpr int cW = 4;
constexpr int cL = (cW + 1) * cS; // 5120
constexpr float cEPS = 1e-5f;

typedef short s16x8 __attribute__((ext_vector_type(8)));   // 8 bf16 (4 VGPRs)
typedef float f32x4 __attribute__((ext_vector_type(4)));   // MFMA C/D

__device__ __forceinline__ float u2f(u16 u) {
  union { unsigned int i; float f; } x; x.i = ((unsigned int)u) << 16; return x.f;
}
__device__ __forceinline__ u16 f2u(float f) {
  union { float f; unsigned int i; } x; x.f = f;
  unsigned int i = x.i;
  i += 0x7fffu + ((i >> 16) & 1u); // RNE
  return (u16)(i >> 16);
}
// fast path: native v_cvt bf16 (RNE), 1 VALU op
__device__ __forceinline__ u16 f2u_rt(float f) {
  union { __bf16 b; u16 u; } c; c.b = (__bf16)f; return c.u;
}
__device__ __forceinline__ s16x8 ld_frag(const u16* p) {
  uint4 v = *(const uint4*)p;
  union { uint4 u; s16x8 s; } c; c.u = v; return c.s;
}
__device__ __forceinline__ s16x8 u4_frag(uint4 v) {
  union { uint4 u; s16x8 s; } c; c.u = v; return c.s;
}
// async 16B global -> LDS (dest = wave-uniform base + lane*16)
__device__ __forceinline__ void gl_lds16(const u16* g, u16* l) {
  __builtin_amdgcn_global_load_lds(
      (const __attribute__((address_space(1))) unsigned int*)g,
      (__attribute__((address_space(3))) unsigned int*)l, 16, 0, 0);
}
// VALU-pipe cross-lane fmax via DPP (ctrl must be a literal -> template param)
template <int CTRL>
__device__ __forceinline__ float dpp_fmax(float x) {
  union { float f; int i; } a, r;
  a.f = x;
  r.i = __builtin_amdgcn_update_dpp(a.i, a.i, CTRL, 0xF, 0xF, true);
  return fmaxf(x, r.f);
}

// ---------------- LayerNorm f32 -> f32 (final LN) ----------------
__global__ __launch_bounds__(256) void ln_f32(
    const float* __restrict__ src, float* __restrict__ dst,
    const float* __restrict__ scale, const float* __restrict__ bias)
{
  int r = blockIdx.x;
  int t = threadIdx.x;
  const float* sp = src + (size_t)r * cH;
  float4 x = ((const float4*)sp)[t];
  float s1 = x.x + x.y + x.z + x.w;
  float s2 = x.x * x.x + x.y * x.y + x.z * x.z + x.w * x.w;
  #pragma unroll
  for (int off = 32; off > 0; off >>= 1) {
    s1 += __shfl_down(s1, off);
    s2 += __shfl_down(s2, off);
  }
  __shared__ float w1[4], w2[4];
  __shared__ float stat[2];
  int wid = t >> 6, lid = t & 63;
  if (lid == 0) { w1[wid] = s1; w2[wid] = s2; }
  __syncthreads();
  if (t == 0) {
    float a = w1[0] + w1[1] + w1[2] + w1[3];
    float b = w2[0] + w2[1] + w2[2] + w2[3];
    float mu = a * (1.f / cH);
    float var = b * (1.f / cH) - mu * mu;
    if (var < 0.f) var = 0.f;
    stat[0] = mu; stat[1] = rsqrtf(var + cEPS);
  }
  __syncthreads();
  float mu = stat[0], rs = stat[1];
  int h0 = t * 4;
  float4 sc = *(const float4*)(scale + h0);
  float4 bi = *(const float4*)(bias + h0);
  float4 o;
  o.x = (x.x - mu) * rs * sc.x + bi.x;
  o.y = (x.y - mu) * rs * sc.y + bi.y;
  o.z = (x.z - mu) * rs * sc.z + bi.z;
  o.w = (x.w - mu) * rs * sc.w + bi.w;
  *(float4*)(dst + (size_t)r * cH + h0) = o;
}

// ---------------- LayerNorm f32 -> bf16 into kvin tail ----------------
__global__ __launch_bounds__(256) void ln_bf16(
    const float* __restrict__ src, u16* __restrict__ kvin,
    const float* __restrict__ scale, const float* __restrict__ bias)
{
  int r = blockIdx.x;            // 0..cB*cS-1
  int t = threadIdx.x;
  const float* sp = src + (size_t)r * cH;
  float4 x = ((const float4*)sp)[t];
  float s1 = x.x + x.y + x.z + x.w;
  float s2 = x.x * x.x + x.y * x.y + x.z * x.z + x.w * x.w;
  #pragma unroll
  for (int off = 32; off > 0; off >>= 1) {
    s1 += __shfl_down(s1, off);
    s2 += __shfl_down(s2, off);
  }
  __shared__ float w1[4], w2[4];
  __shared__ float stat[2];
  int wid = t >> 6, lid = t & 63;
  if (lid == 0) { w1[wid] = s1; w2[wid] = s2; }
  __syncthreads();
  if (t == 0) {
    float a = w1[0] + w1[1] + w1[2] + w1[3];
    float b = w2[0] + w2[1] + w2[2] + w2[3];
    float mu = a * (1.f / cH);
    float var = b * (1.f / cH) - mu * mu;
    if (var < 0.f) var = 0.f;
    stat[0] = mu; stat[1] = rsqrtf(var + cEPS);
  }
  __syncthreads();
  float mu = stat[0], rs = stat[1];
  int h0 = t * 4;
  float4 sc = *(const float4*)(scale + h0);
  float4 bi = *(const float4*)(bias + h0);
  int b = r >> 10, s = r & (cS - 1);
  u16* dp = kvin + ((size_t)(b * cL + cW * cS + s)) * cH + h0;
  ushort4 o; u16* op = (u16*)&o;
  op[0] = f2u((x.x - mu) * rs * sc.x + bi.x);
  op[1] = f2u((x.y - mu) * rs * sc.y + bi.y);
  op[2] = f2u((x.z - mu) * rs * sc.z + bi.z);
  op[3] = f2u((x.w - mu) * rs * sc.w + bi.w);
  *(ushort4*)dp = o;
}

// -------- cache f32 [W,B,S,H] -> kvin bf16 [B, w*S+s, H] --------
__global__ __launch_bounds__(256) void cache2kv(const float* __restrict__ cache,
                                                u16* __restrict__ kvin) {
  int blk = blockIdx.x;          // cB*cW*cS = 8192
  int b = blk >> 12, w = (blk >> 10) & 3, s = blk & 1023;
  const float* src = cache + ((size_t)((w * cB + b) * cS + s)) * cH;
  u16* dst = kvin + ((size_t)(b * cL + w * cS + s)) * cH;
  int t = threadIdx.x;
  float4 v = *(const float4*)(src + t * 4);
  ushort4 o; u16* op = (u16*)&o;
  op[0] = f2u(v.x); op[1] = f2u(v.y); op[2] = f2u(v.z); op[3] = f2u(v.w);
  *(ushort4*)(dst + t * 4) = o;
}

// -------- weight transpose: W f32 [k][n] -> Wt bf16 [n][k], 4 matrices --------
__global__ __launch_bounds__(256) void wtrans(
    const float* __restrict__ W0, const float* __restrict__ W1,
    const float* __restrict__ W2, const float* __restrict__ W3,
    u16* __restrict__ Wt)
{
  __shared__ float tile[32][33];
  int mat = blockIdx.z;
  const float* W = (mat == 0) ? W0 : (mat == 1) ? W1 : (mat == 2) ? W2 : W3;
  u16* out = Wt + (size_t)mat * cH * cH;
  int k0 = blockIdx.y * 32, n0 = blockIdx.x * 32;
  int t = threadIdx.x;
  int r = t >> 3, c = (t & 7) * 4;
  float4 v = *(const float4*)(W + (size_t)(k0 + r) * cH + n0 + c);
  tile[r][c] = v.x; tile[r][c + 1] = v.y; tile[r][c + 2] = v.z; tile[r][c + 3] = v.w;
  __syncthreads();
  ushort4 o; u16* op = (u16*)&o;
  #pragma unroll
  for (int j = 0; j < 4; j++) op[j] = f2u(tile[c + j][r]);
  *(ushort4*)(out + (size_t)(n0 + r) * cH + k0 + c) = o;
}

// ---------------- MFMA GEMM: C[M,1024] = A(bf16)[M,1024] @ W, Wt=[n][k] bf16 ----------------
// K-loop: m97-style — global_load_lds(16B) direct into linear [128][32] LDS
// tiles, double-buffered, counted vmcnt(4), raw barriers.
// mode 5: fused K|V projection — Wt spans 2048 rows (Wk then Wv); n0<1024 -> K
// epilogue (mode1 -> Cb), n0>=1024 -> V epilogue (mode3 -> Cb2, n-1024).
constexpr int GBM = 128, GBN = 128, TLD = 136;

__global__ __launch_bounds__(256) void mgemm(
    const u16* __restrict__ A, const u16* __restrict__ Wt,
    int a_rpb, int a_base, int a_stride,
    int c_rpb, int mode,
    u16* __restrict__ Cb, u16* __restrict__ Cb2,
    const float* __restrict__ hidden, const float* __restrict__ cachefull,
    const float* __restrict__ gate, const float* __restrict__ lsc,
    float* __restrict__ outp)
{
  // 17408 u16 = 34.8 KB; staging dbuf occupies the first 16384 u16 (32 KB):
  //   A buf0 @0, A buf1 @4096, B buf0 @8192, B buf1 @12288  (each [128][32] u16)
  // mode-3 epilogue reuses the whole thing as t2[128][TLD] after a vmcnt(0) drain.
  __shared__ __align__(16) u16 smem[128 * TLD];

  int t = threadIdx.x;
  int m0 = blockIdx.y * GBM, n0 = blockIdx.x * GBN;
  int wave = t >> 6, lane = t & 63, l15 = lane & 15, quad = lane >> 4;
  int wm = (wave >> 1) * 64, wn = (wave & 1) * 64;

  // staging source pointers: thread t covers row (t>>2), bytes (t&3)*16 of a
  // 64B row-chunk; dest = linear LDS byte t*16 (wave-uniform base + lane*16).
  int sr = t >> 2, sk = (t & 3) * 8;
  int rg0 = m0 + sr, rg1 = rg0 + 64;
  int ab0 = rg0 / a_rpb, ab1 = rg1 / a_rpb;
  const u16* arow0 = A + (size_t)(ab0 * a_stride + a_base + (rg0 - ab0 * a_rpb)) * cH + sk;
  const u16* arow1 = A + (size_t)(ab1 * a_stride + a_base + (rg1 - ab1 * a_rpb)) * cH + sk;
  const u16* wrow0 = Wt + (size_t)(n0 + sr) * cH + sk;
  const u16* wrow1 = Wt + (size_t)(n0 + sr + 64) * cH + sk;

  u16* As0 = smem;
  u16* Bs0 = smem + 8192;
  int wofs = wave * 512;       // u16; wave-uniform dest base within half-tile

  f32x4 acc[4][4] = {};

  // prologue: stage tile 0 into buffer 0
  gl_lds16(arow0, As0 + wofs);
  gl_lds16(arow1, As0 + 2048 + wofs);
  gl_lds16(wrow0, Bs0 + wofs);
  gl_lds16(wrow1, Bs0 + 2048 + wofs);

  constexpr int NK = cH / 32;  // 32 K-steps
  for (int kt = 0; kt < NK; kt++) {
    int cur = kt & 1;
    // barrier A: all waves done reading buf cur^1 (previous iteration)
    asm volatile("" ::: "memory");
    __builtin_amdgcn_s_barrier();
    asm volatile("" ::: "memory");
    // prefetch next tile into buf cur^1
    int nk = kt + 1; if (nk == NK) nk = 0;
    int nko = nk * 32;
    u16* Abn = As0 + (cur ^ 1) * 4096;
    u16* Bbn = Bs0 + (cur ^ 1) * 4096;
    gl_lds16(arow0 + nko, Abn + wofs);
    gl_lds16(arow1 + nko, Abn + 2048 + wofs);
    gl_lds16(wrow0 + nko, Bbn + wofs);
    gl_lds16(wrow1 + nko, Bbn + 2048 + wofs);
    // wait own stage of tile kt (4 newer outstanding = the prefetch just issued)
    asm volatile("s_waitcnt vmcnt(4)" ::: "memory");
    __builtin_amdgcn_s_barrier();
    asm volatile("" ::: "memory");
    // fragments from buf cur (linear [128][32], row stride 64B)
    const u16* Ab = As0 + cur * 4096;
    const u16* Bb = Bs0 + cur * 4096;
    s16x8 af[4], bf[4];
    #pragma unroll
    for (int mt = 0; mt < 4; mt++)
      af[mt] = *(const s16x8*)&Ab[(wm + mt * 16 + l15) * 32 + quad * 8];
    #pragma unroll
    for (int nt = 0; nt < 4; nt++)
      bf[nt] = *(const s16x8*)&Bb[(wn + nt * 16 + l15) * 32 + quad * 8];
    #pragma unroll
    for (int mt = 0; mt < 4; mt++)
      #pragma unroll
      for (int nt = 0; nt < 4; nt++)
        acc[mt][nt] = __builtin_amdgcn_mfma_f32_16x16x32_bf16(af[mt], bf[nt], acc[mt][nt], 0, 0, 0);
  }

  int mode_eff = mode;
  u16* Cout = Cb;
  int nbase = n0;
  if (mode == 5) {
    if (n0 < cH) { mode_eff = 1; }
    else { mode_eff = 3; Cout = Cb2; nbase = n0 - cH; }
  }

  if (mode_eff == 1) {
    #pragma unroll
    for (int mt = 0; mt < 4; mt++)
      #pragma unroll
      for (int i = 0; i < 4; i++) {
        int rg = m0 + wm + mt * 16 + quad * 4 + i;
        int bo = rg / c_rpb, lo = rg - bo * c_rpb;
        #pragma unroll
        for (int nt = 0; nt < 4; nt++) {
          int n = nbase + wn + nt * 16 + l15;
          int h = n >> 6, d = n & 63;
          Cout[(((size_t)(bo * cNH + h) * c_rpb + lo) * cHD) + d] = f2u(acc[mt][nt][i]);
        }
      }
  } else if (mode_eff == 3) {
    u16* t2 = smem;
    // drain wrap-around prefetch before reusing LDS
    asm volatile("s_waitcnt vmcnt(0)" ::: "memory");
    __syncthreads();
    #pragma unroll
    for (int mt = 0; mt < 4; mt++)
      #pragma unroll
      for (int nt = 0; nt < 4; nt++) {
        ushort4 o; u16* op = (u16*)&o;
        #pragma unroll
        for (int i = 0; i < 4; i++) op[i] = f2u(acc[mt][nt][i]);
        *(ushort4*)&t2[(size_t)(wn + nt * 16 + l15) * TLD + wm + mt * 16 + quad * 4] = o;
      }
    __syncthreads();
    int n_l = t >> 1, mh = (t & 1) * 64;
    int bo = m0 / c_rpb;
    int lo = m0 - bo * c_rpb + mh;
    int n = nbase + n_l, h = n >> 6, d = n & 63;
    u16* dst = Cout + ((size_t)(bo * cNH + h) * cHD + d) * (size_t)c_rpb + lo;
    #pragma unroll
    for (int j = 0; j < 8; j++)
      *(uint4*)(dst + j * 8) = *(const uint4*)&t2[(size_t)n_l * TLD + mh + j * 8];
  } else {
    float gv[4], lv[4];
    #pragma unroll
    for (int nt = 0; nt < 4; nt++) {
      int n = n0 + wn + nt * 16 + l15;
      gv[nt] = 1.f / (1.f + __expf(-gate[n]));
      lv[nt] = lsc[n];
    }
    #pragma unroll
    for (int mt = 0; mt < 4; mt++)
      #pragma unroll
      for (int i = 0; i < 4; i++) {
        int rg = m0 + wm + mt * 16 + quad * 4 + i;
        size_t rbase = (size_t)rg * cH;
        #pragma unroll
        for (int nt = 0; nt < 4; nt++) {
          int n = n0 + wn + nt * 16 + l15;
          float hid = hidden[rbase + n];
          float cr = cachefull[(size_t)3 * cB * cS * cH + rbase + n];
          outp[rbase + n] = hid + lv[nt] * (gv[nt] * acc[mt][nt][i] + (1.f - gv[nt]) * cr);
        }
      }
  }
}

// ---------------- RoPE in-place on head-major bf16 [b*h][rows][64] ----------------
__global__ __launch_bounds__(256) void rope_b16(u16* __restrict__ X, int rows) {
  size_t idx = (size_t)blockIdx.x * 256 + threadIdx.x;
  int d = (int)(idx & 31);
  size_t rest = idx >> 5;
  int row = (int)(rest % rows);
  size_t bh = rest / rows;
  u16* xp = X + (bh * rows + row) * cHD;
  int pos = row & (cS - 1);
  float freq = exp2f(-(float)d * (13.287712379549449f / 32.f)); // 10000^(-d/32)
  float ang = (float)pos * freq;
  float sn, cs;
  sincosf(ang, &sn, &cs);
  float x1 = u2f(xp[d]), x2 = u2f(xp[d + 32]);
  xp[d] = f2u(x1 * cs - x2 * sn);
  xp[d + 32] = f2u(x1 * sn + x2 * cs);
}

// ---------------- MFMA flash attention, split-K over key quarters ----------------
// 2 q-tiles per wave: each wave owns rows [q0,q0+16) and [q0+64,q0+80).
// K staged in LDS (dbuf, swizzled, global_load_lds, counted vmcnt) and its
// ds_read fragments feed BOTH tiles' QK; hoisted V registers feed both PV.
// Two independent softmax chains give intra-wave ILP (waves are reg-capped
// at 4/SIMD, so ILP — not occupancy — is the latency-hiding lever).
constexpr int ACK = 64;
constexpr int PLD = 72;
constexpr int KSPLIT = 4;
constexpr int KS = cL / KSPLIT;      // 1280 keys per split
constexpr int NIT = KS / ACK;        // 20 tiles
constexpr int NRB = cB * cNH * cS;   // rows per split (32768)

__global__ __launch_bounds__(256, 4) void attn_mfma(
    const u16* __restrict__ Q, const u16* __restrict__ K, const u16* __restrict__ Vt,
    float* __restrict__ o0, float* __restrict__ o1,
    float* __restrict__ o2, float* __restrict__ o3,
    float* __restrict__ mlbuf)
{
  // K: 2 x 8 KB, XOR-swizzled.  P: per wave, 2 tiles x [16][PLD].
  __shared__ __align__(16) u16 kls[2][ACK * cHD];     // 16 KB
  __shared__ u16 pbuf[4][2][16 * PLD];                // 18.4 KB

  int t = threadIdx.x;
  int wave = t >> 6, lane = t & 63;
  int l15 = lane & 15, quad = lane >> 4;
  int qt = blockIdx.x, h = blockIdx.y;
  int bz = blockIdx.z;
  int b = bz & (cB - 1), split = bz >> 1;
  int q0a = qt * 128 + wave * 16;
  int q0b = q0a + 64;
  int kbase = split * KS;

  const u16* qpa = Q + ((size_t)(b * cNH + h) * cS + q0a) * cHD;
  const u16* qpb = qpa + (size_t)64 * cHD;
  const char* kp = (const char*)(K + ((size_t)(b * cNH + h) * cL + kbase) * cHD);
  const u16* vp = Vt + (size_t)(b * cNH + h) * cHD * cL + kbase;
  u16* pwA = &pbuf[wave][0][0];
  u16* pwB = &pbuf[wave][1][0];

  // staging geometry (unchanged from verified r2-r6 kernel)
  int P0 = wave * 1024 + lane * 16;
  int P1 = P0 + 4096;
  int s0 = P0 ^ (((P0 >> 7) & 7) << 4);
  int s1 = P1 ^ (((P1 >> 7) & 7) << 4);
  int fsw0 = (quad * 16) ^ ((l15 & 7) << 4);
  int fsw1 = (64 + quad * 16) ^ ((l15 & 7) << 4);

  s16x8 qa0 = ld_frag(qpa + (size_t)l15 * cHD + quad * 8);
  s16x8 qa1 = ld_frag(qpa + (size_t)l15 * cHD + 32 + quad * 8);
  s16x8 qb0f = ld_frag(qpb + (size_t)l15 * cHD + quad * 8);
  s16x8 qb1f = ld_frag(qpb + (size_t)l15 * cHD + 32 + quad * 8);

  // prologue: stage tile 0 into buffer 0
  gl_lds16((const u16*)(kp + s0), (u16*)((char*)&kls[0][0] + wave * 1024));
  gl_lds16((const u16*)(kp + s1), (u16*)((char*)&kls[0][0] + 4096 + wave * 1024));

  f32x4 oacc[2][4] = {};
  float mrowA[4], lrowA[4], mrowB[4], lrowB[4];
  #pragma unroll
  for (int i = 0; i < 4; i++) {
    mrowA[i] = -1e30f; lrowA[i] = 0.f;
    mrowB[i] = -1e30f; lrowB[i] = 0.f;
  }

  constexpr float SCL = 0.125f * 1.4426950408889634f;

  for (int kt = 0; kt < NIT; kt++) {
    int cur = kt & 1;
    // ---- V loads, d-tiles 0..1 (shared by both q-tiles) ----
    uint4 v01[4];
    #pragma unroll
    for (int dt = 0; dt < 2; dt++) {
      const u16* vr = vp + (size_t)(dt * 16 + l15) * cL + kt * ACK;
      v01[2 * dt]     = *(const uint4*)(vr + quad * 8);
      v01[2 * dt + 1] = *(const uint4*)(vr + 32 + quad * 8);
    }
    // ---- barrier A: all waves done reading kls[cur^1] (prev iter) ----
    asm volatile("" ::: "memory");
    __builtin_amdgcn_s_barrier();
    asm volatile("" ::: "memory");
    // ---- stage next tile into kls[cur^1] ----
    int nk = kt + 1; if (nk == NIT) nk = 0;
    const char* kn = kp + (size_t)nk * (ACK * cHD * 2);
    gl_lds16((const u16*)(kn + s0), (u16*)((char*)&kls[cur ^ 1][0] + wave * 1024));
    gl_lds16((const u16*)(kn + s1), (u16*)((char*)&kls[cur ^ 1][0] + 4096 + wave * 1024));
    // ---- wait own stage of tile kt (6 newer: 4 V + 2 stage-next) ----
    asm volatile("s_waitcnt vmcnt(6)" ::: "memory");
    __builtin_amdgcn_s_barrier();
    asm volatile("" ::: "memory");
    // ---- QK^T for both q-tiles; K fragments read ONCE, used twice ----
    const char* kc = (const char*)&kls[cur][0];
    f32x4 scA[4], scB[4];
    __builtin_amdgcn_s_setprio(1);
    #pragma unroll
    for (int nt = 0; nt < 4; nt++) {
      s16x8 kf0 = *(const s16x8*)(kc + (nt * 16 + l15) * 128 + fsw0);
      s16x8 kf1 = *(const s16x8*)(kc + (nt * 16 + l15) * 128 + fsw1);
      f32x4 a = {};
      a = __builtin_amdgcn_mfma_f32_16x16x32_bf16(qa0, kf0, a, 0, 0, 0);
      a = __builtin_amdgcn_mfma_f32_16x16x32_bf16(qa1, kf1, a, 0, 0, 0);
      scA[nt] = a * SCL;
      f32x4 c = {};
      c = __builtin_amdgcn_mfma_f32_16x16x32_bf16(qb0f, kf0, c, 0, 0, 0);
      c = __builtin_amdgcn_mfma_f32_16x16x32_bf16(qb1f, kf1, c, 0, 0, 0);
      scB[nt] = c * SCL;
    }
    __builtin_amdgcn_s_setprio(0);
    // ---- softmax (two independent chains: A and B interleave on the VALU) ----
    float mxA[4], mxB[4];
    #pragma unroll
    for (int i = 0; i < 4; i++) {
      mxA[i] = fmaxf(fmaxf(scA[0][i], scA[1][i]), fmaxf(scA[2][i], scA[3][i]));
      mxB[i] = fmaxf(fmaxf(scB[0][i], scB[1][i]), fmaxf(scB[2][i], scB[3][i]));
    }
    #pragma unroll
    for (int i = 0; i < 4; i++) {
      mxA[i] = dpp_fmax<0xB1>(mxA[i]);  mxB[i] = dpp_fmax<0xB1>(mxB[i]);
      mxA[i] = dpp_fmax<0x4E>(mxA[i]);  mxB[i] = dpp_fmax<0x4E>(mxB[i]);
      mxA[i] = dpp_fmax<0x141>(mxA[i]); mxB[i] = dpp_fmax<0x141>(mxB[i]);
      mxA[i] = dpp_fmax<0x140>(mxA[i]); mxB[i] = dpp_fmax<0x140>(mxB[i]);
    }
    bool needA = (mxA[0] > mrowA[0]) | (mxA[1] > mrowA[1]) |
                 (mxA[2] > mrowA[2]) | (mxA[3] > mrowA[3]);
    if (__any(needA)) {
      float alpha[4];
      #pragma unroll
      for (int i = 0; i < 4; i++) {
        float mn = fmaxf(mrowA[i], mxA[i]);
        alpha[i] = exp2f(mrowA[i] - mn);
        mrowA[i] = mn;
        lrowA[i] *= alpha[i];
      }
      #pragma unroll
      for (int dt = 0; dt < 4; dt++)
        #pragma unroll
        for (int i = 0; i < 4; i++) oacc[0][dt][i] *= alpha[i];
    }
    bool needB = (mxB[0] > mrowB[0]) | (mxB[1] > mrowB[1]) |
                 (mxB[2] > mrowB[2]) | (mxB[3] > mrowB[3]);
    if (__any(needB)) {
      float alpha[4];
      #pragma unroll
      for (int i = 0; i < 4; i++) {
        float mn = fmaxf(mrowB[i], mxB[i]);
        alpha[i] = exp2f(mrowB[i] - mn);
        mrowB[i] = mn;
        lrowB[i] *= alpha[i];
      }
      #pragma unroll
      for (int dt = 0; dt < 4; dt++)
        #pragma unroll
        for (int i = 0; i < 4; i++) oacc[1][dt][i] *= alpha[i];
    }
    // ---- P-A: exp2 + pack + LDS write ----
    {
      float ps[4] = {};
      #pragma unroll
      for (int nt = 0; nt < 4; nt++)
        #pragma unroll
        for (int i = 0; i < 4; i++) {
          float p = exp2f(scA[nt][i] - mrowA[i]);
          ps[i] += p;
          pwA[(quad * 4 + i) * PLD + nt * 16 + l15] = f2u_rt(p);
        }
      #pragma unroll
      for (int i = 0; i < 4; i++) lrowA[i] += ps[i];
    }
    // ---- V loads, d-tiles 2..3 (latency covered by P-B + PV-01 below) ----
    uint4 v23[4];
    #pragma unroll
    for (int dt = 2; dt < 4; dt++) {
      const u16* vr = vp + (size_t)(dt * 16 + l15) * cL + kt * ACK;
      v23[2 * (dt - 2)]     = *(const uint4*)(vr + quad * 8);
      v23[2 * (dt - 2) + 1] = *(const uint4*)(vr + 32 + quad * 8);
    }
    // ---- P-B ----
    {
      float ps[4] = {};
      #pragma unroll
      for (int nt = 0; nt < 4; nt++)
        #pragma unroll
        for (int i = 0; i < 4; i++) {
          float p = exp2f(scB[nt][i] - mrowB[i]);
          ps[i] += p;
          pwB[(quad * 4 + i) * PLD + nt * 16 + l15] = f2u_rt(p);
        }
      #pragma unroll
      for (int i = 0; i < 4; i++) lrowB[i] += ps[i];
    }
    // ---- PV for both tiles ----
    s16x8 pfA0 = *(const s16x8*)&pwA[l15 * PLD + quad * 8];
    s16x8 pfA1 = *(const s16x8*)&pwA[l15 * PLD + 32 + quad * 8];
    s16x8 pfB0 = *(const s16x8*)&pwB[l15 * PLD + quad * 8];
    s16x8 pfB1 = *(const s16x8*)&pwB[l15 * PLD + 32 + quad * 8];
    __builtin_amdgcn_s_setprio(1);
    #pragma unroll
    for (int dt = 0; dt < 2; dt++) {
      oacc[0][dt] = __builtin_amdgcn_mfma_f32_16x16x32_bf16(pfA0, u4_frag(v01[2 * dt]), oacc[0][dt], 0, 0, 0);
      oacc[0][dt] = __builtin_amdgcn_mfma_f32_16x16x32_bf16(pfA1, u4_frag(v01[2 * dt + 1]), oacc[0][dt], 0, 0, 0);
      oacc[1][dt] = __builtin_amdgcn_mfma_f32_16x16x32_bf16(pfB0, u4_frag(v01[2 * dt]), oacc[1][dt], 0, 0, 0);
      oacc[1][dt] = __builtin_amdgcn_mfma_f32_16x16x32_bf16(pfB1, u4_frag(v01[2 * dt + 1]), oacc[1][dt], 0, 0, 0);
    }
    #pragma unroll
    for (int dt = 2; dt < 4; dt++) {
      int vi = 2 * (dt - 2);
      oacc[0][dt] = __builtin_amdgcn_mfma_f32_16x16x32_bf16(pfA0, u4_frag(v23[vi]), oacc[0][dt], 0, 0, 0);
      oacc[0][dt] = __builtin_amdgcn_mfma_f32_16x16x32_bf16(pfA1, u4_frag(v23[vi + 1]), oacc[0][dt], 0, 0, 0);
      oacc[1][dt] = __builtin_amdgcn_mfma_f32_16x16x32_bf16(pfB0, u4_frag(v23[vi]), oacc[1][dt], 0, 0, 0);
      oacc[1][dt] = __builtin_amdgcn_mfma_f32_16x16x32_bf16(pfB1, u4_frag(v23[vi + 1]), oacc[1][dt], 0, 0, 0);
    }
    __builtin_amdgcn_s_setprio(0);
  }
  // ---- final l-reduce across the 16-lane key group ----
  #pragma unroll
  for (int off = 1; off < 16; off <<= 1)
    #pragma unroll
    for (int i = 0; i < 4; i++) {
      lrowA[i] += __shfl_xor(lrowA[i], off);
      lrowB[i] += __shfl_xor(lrowB[i], off);
    }
  // ---- epilogue: unnormalized partial O + (m,l) for both tiles ----
  float* ob = (split == 0) ? o0 : (split == 1) ? o1 : (split == 2) ? o2 : o3;
  #pragma unroll
  for (int x = 0; x < 2; x++) {
    int qbase = x ? q0b : q0a;
    #pragma unroll
    for (int i = 0; i < 4; i++) {
      int q = qbase + quad * 4 + i;
      size_t Rl = (size_t)(b * cNH + h) * cS + q;
      float* orow = ob + Rl * cHD;
      #pragma unroll
      for (int dt = 0; dt < 4; dt++)
        orow[dt * 16 + l15] = oacc[x][dt][i];
      if (l15 == 0) {
        mlbuf[((size_t)split * NRB + Rl) * 2]     = x ? mrowB[i] : mrowA[i];
        mlbuf[((size_t)split * NRB + Rl) * 2 + 1] = x ? lrowB[i] : lrowA[i];
      }
    }
  }
}

// ---------------- split-K merge: combine four softmax partials -> bf16 ctx ----------------
__global__ __launch_bounds__(256) void attn_merge(
    const float* __restrict__ o0, const float* __restrict__ o1,
    const float* __restrict__ o2, const float* __restrict__ o3,
    const float* __restrict__ mlbuf, u16* __restrict__ ctx)
{
  int t = threadIdx.x;
  int R = blockIdx.x * 4 + (t >> 6);   // (b*cNH+h)*cS + q
  int d = t & 63;
  float ms[KSPLIT], ls[KSPLIT];
  float m = -1e30f;
  #pragma unroll
  for (int s = 0; s < KSPLIT; s++) {
    ms[s] = mlbuf[((size_t)s * NRB + R) * 2];
    ls[s] = mlbuf[((size_t)s * NRB + R) * 2 + 1];
    m = fmaxf(m, ms[s]);
  }
  const float* ops[KSPLIT] = {o0, o1, o2, o3};
  float num = 0.f, den = 0.f;
  #pragma unroll
  for (int s = 0; s < KSPLIT; s++) {
    float a = exp2f(ms[s] - m);
    num += ops[s][(size_t)R * cHD + d] * a;
    den += ls[s] * a;
  }
  float val = num / den;
  int q = R & (cS - 1), h = (R >> 10) & 15, b = R >> 14;
  ctx[((size_t)b * cS + q) * cH + h * cHD + d] = f2u(val);
}

extern "C" void kernel_launch(void* const* d_in, const int* in_sizes, int n_in,
                              void* d_out, int out_size, void* d_ws, size_t ws_size,
                              hipStream_t stream)
{
  const float* hidden = (const float*)d_in[0];
  const float* cache  = (const float*)d_in[1];
  const float* ln_s   = (const float*)d_in[2];
  const float* ln_b   = (const float*)d_in[3];
  const float* Wq     = (const float*)d_in[4];
  const float* Wk     = (const float*)d_in[5];
  const float* Wv     = (const float*)d_in[6];
  const float* Wo     = (const float*)d_in[7];
  const float* gate   = (const float*)d_in[8];
  const float* lsc    = (const float*)d_in[9];
  float* outp = (float*)d_out;

  // ws: kvin 20.97M | vt 20.97M | opart(splits 0,1) 16.78M  (~58.7 MB)
  u16* kvin = (u16*)d_ws;
  u16* vt   = kvin + (size_t)cB * cL * cH;
  float* opart = (float*)(vt + (size_t)cB * cL * cH);
  float* o0 = opart;
  float* o1 = opart + (size_t)cB * cNH * cS * cHD;          // +8.39MB
  // aliases into kvin (dead rows by the time these are written):
  u16* qb  = kvin;                                // [0, 4.19M) written by Q GEMM (last kvin reader)
  u16* ctx = kvin + (size_t)2 * 1024 * 1024;      // [4.19M, 8.39M) written by attn_merge
  float* o2 = (float*)(kvin + (size_t)4 * 1024 * 1024);   // bytes [8.39M, 16.78M)
  float* mlbuf = (float*)(kvin + (size_t)8 * 1024 * 1024);// bytes [16.78M, 17.83M), 4 splits
  // split-3 opart parked in d_out output region [0, 8.39M) — written by attn,
  // read by merge, then overwritten by the step-7 GEMM epilogue:
  float* o3 = outp;
  // scratch parked in d_out (overwritten by memcpy/final-LN at the end):
  u16* kb = (u16*)(outp + (size_t)cB * cS * cH);
  u16* Wt = (u16*)(outp + (size_t)(1 + 3) * cB * cS * cH);
  u16* Wt_q = Wt;
  u16* Wt_k = Wt + (size_t)cH * cH;
  u16* Wt_v = Wt + (size_t)2 * cH * cH;
  u16* Wt_o = Wt + (size_t)3 * cH * cH;

  // 1) weight transpose+convert
  wtrans<<<dim3(32, 32, 4), 256, 0, stream>>>(Wq, Wk, Wv, Wo, Wt);
  // 2) cache -> kvin head rows (bf16, permuted)
  cache2kv<<<cB * cW * cS, 256, 0, stream>>>(cache, kvin);
  // 3) pre-norm -> kvin tail rows (bf16)
  ln_bf16<<<cB * cS, 256, 0, stream>>>(hidden, kvin, ln_s, ln_b);

  // 4) fused K|V projection (Wt_k,Wt_v contiguous -> one 2048-col GEMM), then Q
  mgemm<<<dim3(16, (cB * cL) / GBM), 256, 0, stream>>>(
      kvin, Wt_k, cL, 0, cL, cL, 5, kb, vt, nullptr, nullptr, nullptr, nullptr, nullptr);
  mgemm<<<dim3(8, (cB * cS) / GBM), 256, 0, stream>>>(
      kvin, Wt_q, cS, cW * cS, cL, cS, 1, qb, nullptr, nullptr, nullptr, nullptr, nullptr, nullptr);

  // 5) RoPE on Q and K
  rope_b16<<<(cB * cNH * cS * 32) / 256, 256, 0, stream>>>(qb, cS);
  rope_b16<<<(cB * cNH * cL * 32) / 256, 256, 0, stream>>>(kb, cL);

  // 6) 4-way split-K MFMA flash attention (2 q-tiles/wave) -> partials -> merge
  attn_mfma<<<dim3(cS / 128, cNH, cB * KSPLIT), 256, 0, stream>>>(
      qb, kb, vt, o0, o1, o2, o3, mlbuf);
  attn_merge<<<(cB * cNH * cS) / 4, 256, 0, stream>>>(o0, o1, o2, o3, mlbuf, ctx);

  // 7) ctx @ Wo with fused gated residual -> output f32
  mgemm<<<dim3(8, (cB * cS) / GBM), 256, 0, stream>>>(
      ctx, Wt_o, cB * cS, 0, cB * cS, cB * cS, 2, nullptr, nullptr,
      hidden, cache, gate, lsc, outp);

  // 8) new_cache[0:3] = cache[1:4]
  hipMemcpyAsync(outp + (size_t)cB * cS * cH, cache + (size_t)cB * cS * cH,
                 (size_t)(cW - 1) * cB * cS * cH * sizeof(float),
                 hipMemcpyDeviceToDevice, stream);
  // 9) final layernorm -> new_cache slot 3
  ln_f32<<<cB * cS, 256, 0, stream>>>(outp, outp + (size_t)cW * cB * cS * cH, ln_s, ln_b);
}

// Round 8
// 396.655 us; speedup vs baseline: 1.1063x; 1.1063x over previous
//
#include <hip/hip_runtime.h>
#include <math.h>

typedef unsigned short u16;

constexpr int cB = 2;
constexpr int cS = 1024;
constexpr int cH = 1024;
constexpr int cNH = 16;
constexpr int cHD = 64;
constexpr int cW = 4;
constexpr int cL = (cW + 1) * cS; // 5120
constexpr float cEPS = 1e-5f;

typedef short s16x8 __attribute__((ext_vector_type(8)));   // 8 bf16 (4 VGPRs)
typedef float f32x4 __attribute__((ext_vector_type(4)));   // MFMA C/D

__device__ __forceinline__ float u2f(u16 u) {
  union { unsigned int i; float f; } x; x.i = ((unsigned int)u) << 16; return x.f;
}
__device__ __forceinline__ u16 f2u(float f) {
  union { float f; unsigned int i; } x; x.f = f;
  unsigned int i = x.i;
  i += 0x7fffu + ((i >> 16) & 1u); // RNE
  return (u16)(i >> 16);
}
// fast path: native v_cvt bf16 (RNE), 1 VALU op
__device__ __forceinline__ u16 f2u_rt(float f) {
  union { __bf16 b; u16 u; } c; c.b = (__bf16)f; return c.u;
}
__device__ __forceinline__ s16x8 ld_frag(const u16* p) {
  uint4 v = *(const uint4*)p;
  union { uint4 u; s16x8 s; } c; c.u = v; return c.s;
}
__device__ __forceinline__ s16x8 u4_frag(uint4 v) {
  union { uint4 u; s16x8 s; } c; c.u = v; return c.s;
}
// async 16B global -> LDS (dest = wave-uniform base + lane*16)
__device__ __forceinline__ void gl_lds16(const u16* g, u16* l) {
  __builtin_amdgcn_global_load_lds(
      (const __attribute__((address_space(1))) unsigned int*)g,
      (__attribute__((address_space(3))) unsigned int*)l, 16, 0, 0);
}
// VALU-pipe cross-lane fmax via DPP (ctrl must be a literal -> template param)
template <int CTRL>
__device__ __forceinline__ float dpp_fmax(float x) {
  union { float f; int i; } a, r;
  a.f = x;
  r.i = __builtin_amdgcn_update_dpp(a.i, a.i, CTRL, 0xF, 0xF, true);
  return fmaxf(x, r.f);
}

// ---------------- LayerNorm f32 -> f32 (final LN) ----------------
__global__ __launch_bounds__(256) void ln_f32(
    const float* __restrict__ src, float* __restrict__ dst,
    const float* __restrict__ scale, const float* __restrict__ bias)
{
  int r = blockIdx.x;
  int t = threadIdx.x;
  const float* sp = src + (size_t)r * cH;
  float4 x = ((const float4*)sp)[t];
  float s1 = x.x + x.y + x.z + x.w;
  float s2 = x.x * x.x + x.y * x.y + x.z * x.z + x.w * x.w;
  #pragma unroll
  for (int off = 32; off > 0; off >>= 1) {
    s1 += __shfl_down(s1, off);
    s2 += __shfl_down(s2, off);
  }
  __shared__ float w1[4], w2[4];
  __shared__ float stat[2];
  int wid = t >> 6, lid = t & 63;
  if (lid == 0) { w1[wid] = s1; w2[wid] = s2; }
  __syncthreads();
  if (t == 0) {
    float a = w1[0] + w1[1] + w1[2] + w1[3];
    float b = w2[0] + w2[1] + w2[2] + w2[3];
    float mu = a * (1.f / cH);
    float var = b * (1.f / cH) - mu * mu;
    if (var < 0.f) var = 0.f;
    stat[0] = mu; stat[1] = rsqrtf(var + cEPS);
  }
  __syncthreads();
  float mu = stat[0], rs = stat[1];
  int h0 = t * 4;
  float4 sc = *(const float4*)(scale + h0);
  float4 bi = *(const float4*)(bias + h0);
  float4 o;
  o.x = (x.x - mu) * rs * sc.x + bi.x;
  o.y = (x.y - mu) * rs * sc.y + bi.y;
  o.z = (x.z - mu) * rs * sc.z + bi.z;
  o.w = (x.w - mu) * rs * sc.w + bi.w;
  *(float4*)(dst + (size_t)r * cH + h0) = o;
}

// ---------------- LayerNorm f32 -> bf16 into kvin tail ----------------
__global__ __launch_bounds__(256) void ln_bf16(
    const float* __restrict__ src, u16* __restrict__ kvin,
    const float* __restrict__ scale, const float* __restrict__ bias)
{
  int r = blockIdx.x;            // 0..cB*cS-1
  int t = threadIdx.x;
  const float* sp = src + (size_t)r * cH;
  float4 x = ((const float4*)sp)[t];
  float s1 = x.x + x.y + x.z + x.w;
  float s2 = x.x * x.x + x.y * x.y + x.z * x.z + x.w * x.w;
  #pragma unroll
  for (int off = 32; off > 0; off >>= 1) {
    s1 += __shfl_down(s1, off);
    s2 += __shfl_down(s2, off);
  }
  __shared__ float w1[4], w2[4];
  __shared__ float stat[2];
  int wid = t >> 6, lid = t & 63;
  if (lid == 0) { w1[wid] = s1; w2[wid] = s2; }
  __syncthreads();
  if (t == 0) {
    float a = w1[0] + w1[1] + w1[2] + w1[3];
    float b = w2[0] + w2[1] + w2[2] + w2[3];
    float mu = a * (1.f / cH);
    float var = b * (1.f / cH) - mu * mu;
    if (var < 0.f) var = 0.f;
    stat[0] = mu; stat[1] = rsqrtf(var + cEPS);
  }
  __syncthreads();
  float mu = stat[0], rs = stat[1];
  int h0 = t * 4;
  float4 sc = *(const float4*)(scale + h0);
  float4 bi = *(const float4*)(bias + h0);
  int b = r >> 10, s = r & (cS - 1);
  u16* dp = kvin + ((size_t)(b * cL + cW * cS + s)) * cH + h0;
  ushort4 o; u16* op = (u16*)&o;
  op[0] = f2u((x.x - mu) * rs * sc.x + bi.x);
  op[1] = f2u((x.y - mu) * rs * sc.y + bi.y);
  op[2] = f2u((x.z - mu) * rs * sc.z + bi.z);
  op[3] = f2u((x.w - mu) * rs * sc.w + bi.w);
  *(ushort4*)dp = o;
}

// -------- cache f32 [W,B,S,H] -> kvin bf16 [B, w*S+s, H] --------
__global__ __launch_bounds__(256) void cache2kv(const float* __restrict__ cache,
                                                u16* __restrict__ kvin) {
  int blk = blockIdx.x;          // cB*cW*cS = 8192
  int b = blk >> 12, w = (blk >> 10) & 3, s = blk & 1023;
  const float* src = cache + ((size_t)((w * cB + b) * cS + s)) * cH;
  u16* dst = kvin + ((size_t)(b * cL + w * cS + s)) * cH;
  int t = threadIdx.x;
  float4 v = *(const float4*)(src + t * 4);
  ushort4 o; u16* op = (u16*)&o;
  op[0] = f2u(v.x); op[1] = f2u(v.y); op[2] = f2u(v.z); op[3] = f2u(v.w);
  *(ushort4*)(dst + t * 4) = o;
}

// -------- weight transpose: W f32 [k][n] -> Wt bf16 [n][k], 4 matrices --------
__global__ __launch_bounds__(256) void wtrans(
    const float* __restrict__ W0, const float* __restrict__ W1,
    const float* __restrict__ W2, const float* __restrict__ W3,
    u16* __restrict__ Wt)
{
  __shared__ float tile[32][33];
  int mat = blockIdx.z;
  const float* W = (mat == 0) ? W0 : (mat == 1) ? W1 : (mat == 2) ? W2 : W3;
  u16* out = Wt + (size_t)mat * cH * cH;
  int k0 = blockIdx.y * 32, n0 = blockIdx.x * 32;
  int t = threadIdx.x;
  int r = t >> 3, c = (t & 7) * 4;
  float4 v = *(const float4*)(W + (size_t)(k0 + r) * cH + n0 + c);
  tile[r][c] = v.x; tile[r][c + 1] = v.y; tile[r][c + 2] = v.z; tile[r][c + 3] = v.w;
  __syncthreads();
  ushort4 o; u16* op = (u16*)&o;
  #pragma unroll
  for (int j = 0; j < 4; j++) op[j] = f2u(tile[c + j][r]);
  *(ushort4*)(out + (size_t)(n0 + r) * cH + k0 + c) = o;
}

// ---------------- MFMA GEMM: C[M,1024] = A(bf16)[M,1024] @ W, Wt=[n][k] bf16 ----------------
// K-loop: m97-style — global_load_lds(16B) direct into linear [128][32] LDS
// tiles, double-buffered, counted vmcnt(4), raw barriers.
// mode 5: fused K|V projection — Wt spans 2048 rows (Wk then Wv); n0<1024 -> K
// epilogue (mode1 -> Cb), n0>=1024 -> V epilogue (mode3 -> Cb2, n-1024).
constexpr int GBM = 128, GBN = 128, TLD = 136;

__global__ __launch_bounds__(256) void mgemm(
    const u16* __restrict__ A, const u16* __restrict__ Wt,
    int a_rpb, int a_base, int a_stride,
    int c_rpb, int mode,
    u16* __restrict__ Cb, u16* __restrict__ Cb2,
    const float* __restrict__ hidden, const float* __restrict__ cachefull,
    const float* __restrict__ gate, const float* __restrict__ lsc,
    float* __restrict__ outp)
{
  // 17408 u16 = 34.8 KB; staging dbuf occupies the first 16384 u16 (32 KB):
  //   A buf0 @0, A buf1 @4096, B buf0 @8192, B buf1 @12288  (each [128][32] u16)
  // mode-3 epilogue reuses the whole thing as t2[128][TLD] after a vmcnt(0) drain.
  __shared__ __align__(16) u16 smem[128 * TLD];

  int t = threadIdx.x;
  int m0 = blockIdx.y * GBM, n0 = blockIdx.x * GBN;
  int wave = t >> 6, lane = t & 63, l15 = lane & 15, quad = lane >> 4;
  int wm = (wave >> 1) * 64, wn = (wave & 1) * 64;

  // staging source pointers: thread t covers row (t>>2), bytes (t&3)*16 of a
  // 64B row-chunk; dest = linear LDS byte t*16 (wave-uniform base + lane*16).
  int sr = t >> 2, sk = (t & 3) * 8;
  int rg0 = m0 + sr, rg1 = rg0 + 64;
  int ab0 = rg0 / a_rpb, ab1 = rg1 / a_rpb;
  const u16* arow0 = A + (size_t)(ab0 * a_stride + a_base + (rg0 - ab0 * a_rpb)) * cH + sk;
  const u16* arow1 = A + (size_t)(ab1 * a_stride + a_base + (rg1 - ab1 * a_rpb)) * cH + sk;
  const u16* wrow0 = Wt + (size_t)(n0 + sr) * cH + sk;
  const u16* wrow1 = Wt + (size_t)(n0 + sr + 64) * cH + sk;

  u16* As0 = smem;
  u16* Bs0 = smem + 8192;
  int wofs = wave * 512;       // u16; wave-uniform dest base within half-tile

  f32x4 acc[4][4] = {};

  // prologue: stage tile 0 into buffer 0
  gl_lds16(arow0, As0 + wofs);
  gl_lds16(arow1, As0 + 2048 + wofs);
  gl_lds16(wrow0, Bs0 + wofs);
  gl_lds16(wrow1, Bs0 + 2048 + wofs);

  constexpr int NK = cH / 32;  // 32 K-steps
  for (int kt = 0; kt < NK; kt++) {
    int cur = kt & 1;
    // barrier A: all waves done reading buf cur^1 (previous iteration)
    asm volatile("" ::: "memory");
    __builtin_amdgcn_s_barrier();
    asm volatile("" ::: "memory");
    // prefetch next tile into buf cur^1
    int nk = kt + 1; if (nk == NK) nk = 0;
    int nko = nk * 32;
    u16* Abn = As0 + (cur ^ 1) * 4096;
    u16* Bbn = Bs0 + (cur ^ 1) * 4096;
    gl_lds16(arow0 + nko, Abn + wofs);
    gl_lds16(arow1 + nko, Abn + 2048 + wofs);
    gl_lds16(wrow0 + nko, Bbn + wofs);
    gl_lds16(wrow1 + nko, Bbn + 2048 + wofs);
    // wait own stage of tile kt (4 newer outstanding = the prefetch just issued)
    asm volatile("s_waitcnt vmcnt(4)" ::: "memory");
    __builtin_amdgcn_s_barrier();
    asm volatile("" ::: "memory");
    // fragments from buf cur (linear [128][32], row stride 64B)
    const u16* Ab = As0 + cur * 4096;
    const u16* Bb = Bs0 + cur * 4096;
    s16x8 af[4], bf[4];
    #pragma unroll
    for (int mt = 0; mt < 4; mt++)
      af[mt] = *(const s16x8*)&Ab[(wm + mt * 16 + l15) * 32 + quad * 8];
    #pragma unroll
    for (int nt = 0; nt < 4; nt++)
      bf[nt] = *(const s16x8*)&Bb[(wn + nt * 16 + l15) * 32 + quad * 8];
    #pragma unroll
    for (int mt = 0; mt < 4; mt++)
      #pragma unroll
      for (int nt = 0; nt < 4; nt++)
        acc[mt][nt] = __builtin_amdgcn_mfma_f32_16x16x32_bf16(af[mt], bf[nt], acc[mt][nt], 0, 0, 0);
  }

  int mode_eff = mode;
  u16* Cout = Cb;
  int nbase = n0;
  if (mode == 5) {
    if (n0 < cH) { mode_eff = 1; }
    else { mode_eff = 3; Cout = Cb2; nbase = n0 - cH; }
  }

  if (mode_eff == 1) {
    #pragma unroll
    for (int mt = 0; mt < 4; mt++)
      #pragma unroll
      for (int i = 0; i < 4; i++) {
        int rg = m0 + wm + mt * 16 + quad * 4 + i;
        int bo = rg / c_rpb, lo = rg - bo * c_rpb;
        #pragma unroll
        for (int nt = 0; nt < 4; nt++) {
          int n = nbase + wn + nt * 16 + l15;
          int h = n >> 6, d = n & 63;
          Cout[(((size_t)(bo * cNH + h) * c_rpb + lo) * cHD) + d] = f2u(acc[mt][nt][i]);
        }
      }
  } else if (mode_eff == 3) {
    u16* t2 = smem;
    // drain wrap-around prefetch before reusing LDS
    asm volatile("s_waitcnt vmcnt(0)" ::: "memory");
    __syncthreads();
    #pragma unroll
    for (int mt = 0; mt < 4; mt++)
      #pragma unroll
      for (int nt = 0; nt < 4; nt++) {
        ushort4 o; u16* op = (u16*)&o;
        #pragma unroll
        for (int i = 0; i < 4; i++) op[i] = f2u(acc[mt][nt][i]);
        *(ushort4*)&t2[(size_t)(wn + nt * 16 + l15) * TLD + wm + mt * 16 + quad * 4] = o;
      }
    __syncthreads();
    int n_l = t >> 1, mh = (t & 1) * 64;
    int bo = m0 / c_rpb;
    int lo = m0 - bo * c_rpb + mh;
    int n = nbase + n_l, h = n >> 6, d = n & 63;
    u16* dst = Cout + ((size_t)(bo * cNH + h) * cHD + d) * (size_t)c_rpb + lo;
    #pragma unroll
    for (int j = 0; j < 8; j++)
      *(uint4*)(dst + j * 8) = *(const uint4*)&t2[(size_t)n_l * TLD + mh + j * 8];
  } else {
    float gv[4], lv[4];
    #pragma unroll
    for (int nt = 0; nt < 4; nt++) {
      int n = n0 + wn + nt * 16 + l15;
      gv[nt] = 1.f / (1.f + __expf(-gate[n]));
      lv[nt] = lsc[n];
    }
    #pragma unroll
    for (int mt = 0; mt < 4; mt++)
      #pragma unroll
      for (int i = 0; i < 4; i++) {
        int rg = m0 + wm + mt * 16 + quad * 4 + i;
        size_t rbase = (size_t)rg * cH;
        #pragma unroll
        for (int nt = 0; nt < 4; nt++) {
          int n = n0 + wn + nt * 16 + l15;
          float hid = hidden[rbase + n];
          float cr = cachefull[(size_t)3 * cB * cS * cH + rbase + n];
          outp[rbase + n] = hid + lv[nt] * (gv[nt] * acc[mt][nt][i] + (1.f - gv[nt]) * cr);
        }
      }
  }
}

// ---------------- RoPE in-place on head-major bf16 [b*h][rows][64] ----------------
__global__ __launch_bounds__(256) void rope_b16(u16* __restrict__ X, int rows) {
  size_t idx = (size_t)blockIdx.x * 256 + threadIdx.x;
  int d = (int)(idx & 31);
  size_t rest = idx >> 5;
  int row = (int)(rest % rows);
  size_t bh = rest / rows;
  u16* xp = X + (bh * rows + row) * cHD;
  int pos = row & (cS - 1);
  float freq = exp2f(-(float)d * (13.287712379549449f / 32.f)); // 10000^(-d/32)
  float ang = (float)pos * freq;
  float sn, cs;
  sincosf(ang, &sn, &cs);
  float x1 = u2f(xp[d]), x2 = u2f(xp[d + 32]);
  xp[d] = f2u(x1 * cs - x2 * sn);
  xp[d + 32] = f2u(x1 * sn + x2 * cs);
}

// ---------------- MFMA flash attention, split-K over key quarters ----------------
// 2 q-tiles per wave, launch_bounds(256,3): ~170-VGPR cap so the 2-tile body
// fits WITHOUT spilling (r7: (256,4)=128-reg cap spilled ~750 MB to scratch).
// 3 blocks/CU instead of 4 — ILP > occupancy for this kernel (r7 evidence).
constexpr int ACK = 64;
constexpr int PLD = 72;
constexpr int KSPLIT = 4;
constexpr int KS = cL / KSPLIT;      // 1280 keys per split
constexpr int NIT = KS / ACK;        // 20 tiles
constexpr int NRB = cB * cNH * cS;   // rows per split (32768)

__global__ __launch_bounds__(256, 3) void attn_mfma(
    const u16* __restrict__ Q, const u16* __restrict__ K, const u16* __restrict__ Vt,
    float* __restrict__ o0, float* __restrict__ o1,
    float* __restrict__ o2, float* __restrict__ o3,
    float* __restrict__ mlbuf)
{
  // K: 2 x 8 KB, XOR-swizzled.  P: per wave, 2 tiles x [16][PLD].
  __shared__ __align__(16) u16 kls[2][ACK * cHD];     // 16 KB
  __shared__ u16 pbuf[4][2][16 * PLD];                // 18.4 KB

  int t = threadIdx.x;
  int wave = t >> 6, lane = t & 63;
  int l15 = lane & 15, quad = lane >> 4;
  int qt = blockIdx.x, h = blockIdx.y;
  int bz = blockIdx.z;
  int b = bz & (cB - 1), split = bz >> 1;
  int q0a = qt * 128 + wave * 16;
  int q0b = q0a + 64;
  int kbase = split * KS;

  const u16* qpa = Q + ((size_t)(b * cNH + h) * cS + q0a) * cHD;
  const u16* qpb = qpa + (size_t)64 * cHD;
  const char* kp = (const char*)(K + ((size_t)(b * cNH + h) * cL + kbase) * cHD);
  const u16* vp = Vt + (size_t)(b * cNH + h) * cHD * cL + kbase;
  u16* pwA = &pbuf[wave][0][0];
  u16* pwB = &pbuf[wave][1][0];

  // staging geometry (unchanged from verified r2-r6 kernel)
  int P0 = wave * 1024 + lane * 16;
  int P1 = P0 + 4096;
  int s0 = P0 ^ (((P0 >> 7) & 7) << 4);
  int s1 = P1 ^ (((P1 >> 7) & 7) << 4);
  int fsw0 = (quad * 16) ^ ((l15 & 7) << 4);
  int fsw1 = (64 + quad * 16) ^ ((l15 & 7) << 4);

  s16x8 qa0 = ld_frag(qpa + (size_t)l15 * cHD + quad * 8);
  s16x8 qa1 = ld_frag(qpa + (size_t)l15 * cHD + 32 + quad * 8);
  s16x8 qb0f = ld_frag(qpb + (size_t)l15 * cHD + quad * 8);
  s16x8 qb1f = ld_frag(qpb + (size_t)l15 * cHD + 32 + quad * 8);

  // prologue: stage tile 0 into buffer 0
  gl_lds16((const u16*)(kp + s0), (u16*)((char*)&kls[0][0] + wave * 1024));
  gl_lds16((const u16*)(kp + s1), (u16*)((char*)&kls[0][0] + 4096 + wave * 1024));

  f32x4 oacc[2][4] = {};
  float mrowA[4], lrowA[4], mrowB[4], lrowB[4];
  #pragma unroll
  for (int i = 0; i < 4; i++) {
    mrowA[i] = -1e30f; lrowA[i] = 0.f;
    mrowB[i] = -1e30f; lrowB[i] = 0.f;
  }

  constexpr float SCL = 0.125f * 1.4426950408889634f;

  for (int kt = 0; kt < NIT; kt++) {
    int cur = kt & 1;
    // ---- V loads, d-tiles 0..1 (shared by both q-tiles) ----
    uint4 v01[4];
    #pragma unroll
    for (int dt = 0; dt < 2; dt++) {
      const u16* vr = vp + (size_t)(dt * 16 + l15) * cL + kt * ACK;
      v01[2 * dt]     = *(const uint4*)(vr + quad * 8);
      v01[2 * dt + 1] = *(const uint4*)(vr + 32 + quad * 8);
    }
    // ---- barrier A: all waves done reading kls[cur^1] (prev iter) ----
    asm volatile("" ::: "memory");
    __builtin_amdgcn_s_barrier();
    asm volatile("" ::: "memory");
    // ---- stage next tile into kls[cur^1] ----
    int nk = kt + 1; if (nk == NIT) nk = 0;
    const char* kn = kp + (size_t)nk * (ACK * cHD * 2);
    gl_lds16((const u16*)(kn + s0), (u16*)((char*)&kls[cur ^ 1][0] + wave * 1024));
    gl_lds16((const u16*)(kn + s1), (u16*)((char*)&kls[cur ^ 1][0] + 4096 + wave * 1024));
    // ---- wait own stage of tile kt (6 newer: 4 V + 2 stage-next) ----
    asm volatile("s_waitcnt vmcnt(6)" ::: "memory");
    __builtin_amdgcn_s_barrier();
    asm volatile("" ::: "memory");
    // ---- QK^T for both q-tiles; K fragments read ONCE, used twice ----
    const char* kc = (const char*)&kls[cur][0];
    f32x4 scA[4], scB[4];
    __builtin_amdgcn_s_setprio(1);
    #pragma unroll
    for (int nt = 0; nt < 4; nt++) {
      s16x8 kf0 = *(const s16x8*)(kc + (nt * 16 + l15) * 128 + fsw0);
      s16x8 kf1 = *(const s16x8*)(kc + (nt * 16 + l15) * 128 + fsw1);
      f32x4 a = {};
      a = __builtin_amdgcn_mfma_f32_16x16x32_bf16(qa0, kf0, a, 0, 0, 0);
      a = __builtin_amdgcn_mfma_f32_16x16x32_bf16(qa1, kf1, a, 0, 0, 0);
      scA[nt] = a * SCL;
      f32x4 c = {};
      c = __builtin_amdgcn_mfma_f32_16x16x32_bf16(qb0f, kf0, c, 0, 0, 0);
      c = __builtin_amdgcn_mfma_f32_16x16x32_bf16(qb1f, kf1, c, 0, 0, 0);
      scB[nt] = c * SCL;
    }
    __builtin_amdgcn_s_setprio(0);
    // ---- softmax (two independent chains: A and B interleave on the VALU) ----
    float mxA[4], mxB[4];
    #pragma unroll
    for (int i = 0; i < 4; i++) {
      mxA[i] = fmaxf(fmaxf(scA[0][i], scA[1][i]), fmaxf(scA[2][i], scA[3][i]));
      mxB[i] = fmaxf(fmaxf(scB[0][i], scB[1][i]), fmaxf(scB[2][i], scB[3][i]));
    }
    #pragma unroll
    for (int i = 0; i < 4; i++) {
      mxA[i] = dpp_fmax<0xB1>(mxA[i]);  mxB[i] = dpp_fmax<0xB1>(mxB[i]);
      mxA[i] = dpp_fmax<0x4E>(mxA[i]);  mxB[i] = dpp_fmax<0x4E>(mxB[i]);
      mxA[i] = dpp_fmax<0x141>(mxA[i]); mxB[i] = dpp_fmax<0x141>(mxB[i]);
      mxA[i] = dpp_fmax<0x140>(mxA[i]); mxB[i] = dpp_fmax<0x140>(mxB[i]);
    }
    bool needA = (mxA[0] > mrowA[0]) | (mxA[1] > mrowA[1]) |
                 (mxA[2] > mrowA[2]) | (mxA[3] > mrowA[3]);
    if (__any(needA)) {
      float alpha[4];
      #pragma unroll
      for (int i = 0; i < 4; i++) {
        float mn = fmaxf(mrowA[i], mxA[i]);
        alpha[i] = exp2f(mrowA[i] - mn);
        mrowA[i] = mn;
        lrowA[i] *= alpha[i];
      }
      #pragma unroll
      for (int dt = 0; dt < 4; dt++)
        #pragma unroll
        for (int i = 0; i < 4; i++) oacc[0][dt][i] *= alpha[i];
    }
    bool needB = (mxB[0] > mrowB[0]) | (mxB[1] > mrowB[1]) |
                 (mxB[2] > mrowB[2]) | (mxB[3] > mrowB[3]);
    if (__any(needB)) {
      float alpha[4];
      #pragma unroll
      for (int i = 0; i < 4; i++) {
        float mn = fmaxf(mrowB[i], mxB[i]);
        alpha[i] = exp2f(mrowB[i] - mn);
        mrowB[i] = mn;
        lrowB[i] *= alpha[i];
      }
      #pragma unroll
      for (int dt = 0; dt < 4; dt++)
        #pragma unroll
        for (int i = 0; i < 4; i++) oacc[1][dt][i] *= alpha[i];
    }
    // ---- P-A: exp2 + pack + LDS write ----
    {
      float ps[4] = {};
      #pragma unroll
      for (int nt = 0; nt < 4; nt++)
        #pragma unroll
        for (int i = 0; i < 4; i++) {
          float p = exp2f(scA[nt][i] - mrowA[i]);
          ps[i] += p;
          pwA[(quad * 4 + i) * PLD + nt * 16 + l15] = f2u_rt(p);
        }
      #pragma unroll
      for (int i = 0; i < 4; i++) lrowA[i] += ps[i];
    }
    // ---- V loads, d-tiles 2..3 (latency covered by P-B + PV-01 below) ----
    uint4 v23[4];
    #pragma unroll
    for (int dt = 2; dt < 4; dt++) {
      const u16* vr = vp + (size_t)(dt * 16 + l15) * cL + kt * ACK;
      v23[2 * (dt - 2)]     = *(const uint4*)(vr + quad * 8);
      v23[2 * (dt - 2) + 1] = *(const uint4*)(vr + 32 + quad * 8);
    }
    // ---- P-B ----
    {
      float ps[4] = {};
      #pragma unroll
      for (int nt = 0; nt < 4; nt++)
        #pragma unroll
        for (int i = 0; i < 4; i++) {
          float p = exp2f(scB[nt][i] - mrowB[i]);
          ps[i] += p;
          pwB[(quad * 4 + i) * PLD + nt * 16 + l15] = f2u_rt(p);
        }
      #pragma unroll
      for (int i = 0; i < 4; i++) lrowB[i] += ps[i];
    }
    // ---- PV for both tiles ----
    s16x8 pfA0 = *(const s16x8*)&pwA[l15 * PLD + quad * 8];
    s16x8 pfA1 = *(const s16x8*)&pwA[l15 * PLD + 32 + quad * 8];
    s16x8 pfB0 = *(const s16x8*)&pwB[l15 * PLD + quad * 8];
    s16x8 pfB1 = *(const s16x8*)&pwB[l15 * PLD + 32 + quad * 8];
    __builtin_amdgcn_s_setprio(1);
    #pragma unroll
    for (int dt = 0; dt < 2; dt++) {
      oacc[0][dt] = __builtin_amdgcn_mfma_f32_16x16x32_bf16(pfA0, u4_frag(v01[2 * dt]), oacc[0][dt], 0, 0, 0);
      oacc[0][dt] = __builtin_amdgcn_mfma_f32_16x16x32_bf16(pfA1, u4_frag(v01[2 * dt + 1]), oacc[0][dt], 0, 0, 0);
      oacc[1][dt] = __builtin_amdgcn_mfma_f32_16x16x32_bf16(pfB0, u4_frag(v01[2 * dt]), oacc[1][dt], 0, 0, 0);
      oacc[1][dt] = __builtin_amdgcn_mfma_f32_16x16x32_bf16(pfB1, u4_frag(v01[2 * dt + 1]), oacc[1][dt], 0, 0, 0);
    }
    #pragma unroll
    for (int dt = 2; dt < 4; dt++) {
      int vi = 2 * (dt - 2);
      oacc[0][dt] = __builtin_amdgcn_mfma_f32_16x16x32_bf16(pfA0, u4_frag(v23[vi]), oacc[0][dt], 0, 0, 0);
      oacc[0][dt] = __builtin_amdgcn_mfma_f32_16x16x32_bf16(pfA1, u4_frag(v23[vi + 1]), oacc[0][dt], 0, 0, 0);
      oacc[1][dt] = __builtin_amdgcn_mfma_f32_16x16x32_bf16(pfB0, u4_frag(v23[vi]), oacc[1][dt], 0, 0, 0);
      oacc[1][dt] = __builtin_amdgcn_mfma_f32_16x16x32_bf16(pfB1, u4_frag(v23[vi + 1]), oacc[1][dt], 0, 0, 0);
    }
    __builtin_amdgcn_s_setprio(0);
  }
  // ---- final l-reduce across the 16-lane key group ----
  #pragma unroll
  for (int off = 1; off < 16; off <<= 1)
    #pragma unroll
    for (int i = 0; i < 4; i++) {
      lrowA[i] += __shfl_xor(lrowA[i], off);
      lrowB[i] += __shfl_xor(lrowB[i], off);
    }
  // ---- epilogue: unnormalized partial O + (m,l) for both tiles ----
  float* ob = (split == 0) ? o0 : (split == 1) ? o1 : (split == 2) ? o2 : o3;
  #pragma unroll
  for (int x = 0; x < 2; x++) {
    int qbase = x ? q0b : q0a;
    #pragma unroll
    for (int i = 0; i < 4; i++) {
      int q = qbase + quad * 4 + i;
      size_t Rl = (size_t)(b * cNH + h) * cS + q;
      float* orow = ob + Rl * cHD;
      #pragma unroll
      for (int dt = 0; dt < 4; dt++)
        orow[dt * 16 + l15] = oacc[x][dt][i];
      if (l15 == 0) {
        mlbuf[((size_t)split * NRB + Rl) * 2]     = x ? mrowB[i] : mrowA[i];
        mlbuf[((size_t)split * NRB + Rl) * 2 + 1] = x ? lrowB[i] : lrowA[i];
      }
    }
  }
}

// ---------------- split-K merge: combine four softmax partials -> bf16 ctx ----------------
__global__ __launch_bounds__(256) void attn_merge(
    const float* __restrict__ o0, const float* __restrict__ o1,
    const float* __restrict__ o2, const float* __restrict__ o3,
    const float* __restrict__ mlbuf, u16* __restrict__ ctx)
{
  int t = threadIdx.x;
  int R = blockIdx.x * 4 + (t >> 6);   // (b*cNH+h)*cS + q
  int d = t & 63;
  float ms[KSPLIT], ls[KSPLIT];
  float m = -1e30f;
  #pragma unroll
  for (int s = 0; s < KSPLIT; s++) {
    ms[s] = mlbuf[((size_t)s * NRB + R) * 2];
    ls[s] = mlbuf[((size_t)s * NRB + R) * 2 + 1];
    m = fmaxf(m, ms[s]);
  }
  const float* ops[KSPLIT] = {o0, o1, o2, o3};
  float num = 0.f, den = 0.f;
  #pragma unroll
  for (int s = 0; s < KSPLIT; s++) {
    float a = exp2f(ms[s] - m);
    num += ops[s][(size_t)R * cHD + d] * a;
    den += ls[s] * a;
  }
  float val = num / den;
  int q = R & (cS - 1), h = (R >> 10) & 15, b = R >> 14;
  ctx[((size_t)b * cS + q) * cH + h * cHD + d] = f2u(val);
}

extern "C" void kernel_launch(void* const* d_in, const int* in_sizes, int n_in,
                              void* d_out, int out_size, void* d_ws, size_t ws_size,
                              hipStream_t stream)
{
  const float* hidden = (const float*)d_in[0];
  const float* cache  = (const float*)d_in[1];
  const float* ln_s   = (const float*)d_in[2];
  const float* ln_b   = (const float*)d_in[3];
  const float* Wq     = (const float*)d_in[4];
  const float* Wk     = (const float*)d_in[5];
  const float* Wv     = (const float*)d_in[6];
  const float* Wo     = (const float*)d_in[7];
  const float* gate   = (const float*)d_in[8];
  const float* lsc    = (const float*)d_in[9];
  float* outp = (float*)d_out;

  // ws: kvin 20.97M | vt 20.97M | opart(splits 0,1) 16.78M  (~58.7 MB)
  u16* kvin = (u16*)d_ws;
  u16* vt   = kvin + (size_t)cB * cL * cH;
  float* opart = (float*)(vt + (size_t)cB * cL * cH);
  float* o0 = opart;
  float* o1 = opart + (size_t)cB * cNH * cS * cHD;          // +8.39MB
  // aliases into kvin (dead rows by the time these are written):
  u16* qb  = kvin;                                // [0, 4.19M) written by Q GEMM (last kvin reader)
  u16* ctx = kvin + (size_t)2 * 1024 * 1024;      // [4.19M, 8.39M) written by attn_merge
  float* o2 = (float*)(kvin + (size_t)4 * 1024 * 1024);   // bytes [8.39M, 16.78M)
  float* mlbuf = (float*)(kvin + (size_t)8 * 1024 * 1024);// bytes [16.78M, 17.83M), 4 splits
  // split-3 opart parked in d_out output region [0, 8.39M) — written by attn,
  // read by merge, then overwritten by the step-7 GEMM epilogue:
  float* o3 = outp;
  // scratch parked in d_out (overwritten by memcpy/final-LN at the end):
  u16* kb = (u16*)(outp + (size_t)cB * cS * cH);
  u16* Wt = (u16*)(outp + (size_t)(1 + 3) * cB * cS * cH);
  u16* Wt_q = Wt;
  u16* Wt_k = Wt + (size_t)cH * cH;
  u16* Wt_v = Wt + (size_t)2 * cH * cH;
  u16* Wt_o = Wt + (size_t)3 * cH * cH;

  // 1) weight transpose+convert
  wtrans<<<dim3(32, 32, 4), 256, 0, stream>>>(Wq, Wk, Wv, Wo, Wt);
  // 2) cache -> kvin head rows (bf16, permuted)
  cache2kv<<<cB * cW * cS, 256, 0, stream>>>(cache, kvin);
  // 3) pre-norm -> kvin tail rows (bf16)
  ln_bf16<<<cB * cS, 256, 0, stream>>>(hidden, kvin, ln_s, ln_b);

  // 4) fused K|V projection (Wt_k,Wt_v contiguous -> one 2048-col GEMM), then Q
  mgemm<<<dim3(16, (cB * cL) / GBM), 256, 0, stream>>>(
      kvin, Wt_k, cL, 0, cL, cL, 5, kb, vt, nullptr, nullptr, nullptr, nullptr, nullptr);
  mgemm<<<dim3(8, (cB * cS) / GBM), 256, 0, stream>>>(
      kvin, Wt_q, cS, cW * cS, cL, cS, 1, qb, nullptr, nullptr, nullptr, nullptr, nullptr, nullptr);

  // 5) RoPE on Q and K
  rope_b16<<<(cB * cNH * cS * 32) / 256, 256, 0, stream>>>(qb, cS);
  rope_b16<<<(cB * cNH * cL * 32) / 256, 256, 0, stream>>>(kb, cL);

  // 6) 4-way split-K MFMA flash attention (2 q-tiles/wave) -> partials -> merge
  attn_mfma<<<dim3(cS / 128, cNH, cB * KSPLIT), 256, 0, stream>>>(
      qb, kb, vt, o0, o1, o2, o3, mlbuf);
  attn_merge<<<(cB * cNH * cS) / 4, 256, 0, stream>>>(o0, o1, o2, o3, mlbuf, ctx);

  // 7) ctx @ Wo with fused gated residual -> output f32
  mgemm<<<dim3(8, (cB * cS) / GBM), 256, 0, stream>>>(
      ctx, Wt_o, cB * cS, 0, cB * cS, cB * cS, 2, nullptr, nullptr,
      hidden, cache, gate, lsc, outp);

  // 8) new_cache[0:3] = cache[1:4]
  hipMemcpyAsync(outp + (size_t)cB * cS * cH, cache + (size_t)cB * cS * cH,
                 (size_t)(cW - 1) * cB * cS * cH * sizeof(float),
                 hipMemcpyDeviceToDevice, stream);
  // 9) final layernorm -> new_cache slot 3
  ln_f32<<<cB * cS, 256, 0, stream>>>(outp, outp + (size_t)cW * cB * cS * cH, ln_s, ln_b);
}

// Round 9
// 373.515 us; speedup vs baseline: 1.1748x; 1.0620x over previous
//
#include <hip/hip_runtime.h>
#include <math.h>

typedef unsigned short u16;

constexpr int cB = 2;
constexpr int cS = 1024;
constexpr int cH = 1024;
constexpr int cNH = 16;
constexpr int cHD = 64;
constexpr int cW = 4;
constexpr int cL = (cW + 1) * cS; // 5120
constexpr float cEPS = 1e-5f;

typedef short s16x8 __attribute__((ext_vector_type(8)));   // 8 bf16 (4 VGPRs)
typedef float f32x4 __attribute__((ext_vector_type(4)));   // MFMA C/D

__device__ __forceinline__ float u2f(u16 u) {
  union { unsigned int i; float f; } x; x.i = ((unsigned int)u) << 16; return x.f;
}
__device__ __forceinline__ u16 f2u(float f) {
  union { float f; unsigned int i; } x; x.f = f;
  unsigned int i = x.i;
  i += 0x7fffu + ((i >> 16) & 1u); // RNE
  return (u16)(i >> 16);
}
// fast path: native v_cvt bf16 (RNE), 1 VALU op
__device__ __forceinline__ u16 f2u_rt(float f) {
  union { __bf16 b; u16 u; } c; c.b = (__bf16)f; return c.u;
}
__device__ __forceinline__ s16x8 ld_frag(const u16* p) {
  uint4 v = *(const uint4*)p;
  union { uint4 u; s16x8 s; } c; c.u = v; return c.s;
}
__device__ __forceinline__ s16x8 u4_frag(uint4 v) {
  union { uint4 u; s16x8 s; } c; c.u = v; return c.s;
}
// async 16B global -> LDS (dest = wave-uniform base + lane*16)
__device__ __forceinline__ void gl_lds16(const u16* g, u16* l) {
  __builtin_amdgcn_global_load_lds(
      (const __attribute__((address_space(1))) unsigned int*)g,
      (__attribute__((address_space(3))) unsigned int*)l, 16, 0, 0);
}
// VALU-pipe cross-lane fmax via DPP (ctrl must be a literal -> template param)
template <int CTRL>
__device__ __forceinline__ float dpp_fmax(float x) {
  union { float f; int i; } a, r;
  a.f = x;
  r.i = __builtin_amdgcn_update_dpp(a.i, a.i, CTRL, 0xF, 0xF, true);
  return fmaxf(x, r.f);
}

// ---------------- LayerNorm f32 -> f32 (final LN) ----------------
__global__ __launch_bounds__(256) void ln_f32(
    const float* __restrict__ src, float* __restrict__ dst,
    const float* __restrict__ scale, const float* __restrict__ bias)
{
  int r = blockIdx.x;
  int t = threadIdx.x;
  const float* sp = src + (size_t)r * cH;
  float4 x = ((const float4*)sp)[t];
  float s1 = x.x + x.y + x.z + x.w;
  float s2 = x.x * x.x + x.y * x.y + x.z * x.z + x.w * x.w;
  #pragma unroll
  for (int off = 32; off > 0; off >>= 1) {
    s1 += __shfl_down(s1, off);
    s2 += __shfl_down(s2, off);
  }
  __shared__ float w1[4], w2[4];
  __shared__ float stat[2];
  int wid = t >> 6, lid = t & 63;
  if (lid == 0) { w1[wid] = s1; w2[wid] = s2; }
  __syncthreads();
  if (t == 0) {
    float a = w1[0] + w1[1] + w1[2] + w1[3];
    float b = w2[0] + w2[1] + w2[2] + w2[3];
    float mu = a * (1.f / cH);
    float var = b * (1.f / cH) - mu * mu;
    if (var < 0.f) var = 0.f;
    stat[0] = mu; stat[1] = rsqrtf(var + cEPS);
  }
  __syncthreads();
  float mu = stat[0], rs = stat[1];
  int h0 = t * 4;
  float4 sc = *(const float4*)(scale + h0);
  float4 bi = *(const float4*)(bias + h0);
  float4 o;
  o.x = (x.x - mu) * rs * sc.x + bi.x;
  o.y = (x.y - mu) * rs * sc.y + bi.y;
  o.z = (x.z - mu) * rs * sc.z + bi.z;
  o.w = (x.w - mu) * rs * sc.w + bi.w;
  *(float4*)(dst + (size_t)r * cH + h0) = o;
}

// ---------------- prep: wtrans(4 mats) + cache2kv + ln_bf16, one launch ----------------
// bid [0,4096): weight transpose f32[k][n] -> bf16[n][k]
// bid [4096,12288): cache f32 [W,B,S,H] -> kvin bf16 head rows
// bid [12288,14336): pre-norm hidden -> kvin tail rows (bf16)
__global__ __launch_bounds__(256) void prep(
    const float* __restrict__ W0, const float* __restrict__ W1,
    const float* __restrict__ W2, const float* __restrict__ W3,
    u16* __restrict__ Wt,
    const float* __restrict__ cache, u16* __restrict__ kvin,
    const float* __restrict__ hidden,
    const float* __restrict__ scale, const float* __restrict__ bias)
{
  __shared__ float tile[32][33];
  __shared__ float red[10];
  int t = threadIdx.x;
  int bid = blockIdx.x;
  if (bid < 4096) {
    int mat = bid >> 10;
    int k0 = ((bid >> 5) & 31) * 32, n0 = (bid & 31) * 32;
    const float* W = (mat == 0) ? W0 : (mat == 1) ? W1 : (mat == 2) ? W2 : W3;
    u16* out = Wt + (size_t)mat * cH * cH;
    int r = t >> 3, c = (t & 7) * 4;
    float4 v = *(const float4*)(W + (size_t)(k0 + r) * cH + n0 + c);
    tile[r][c] = v.x; tile[r][c + 1] = v.y; tile[r][c + 2] = v.z; tile[r][c + 3] = v.w;
    __syncthreads();
    ushort4 o; u16* op = (u16*)&o;
    #pragma unroll
    for (int j = 0; j < 4; j++) op[j] = f2u(tile[c + j][r]);
    *(ushort4*)(out + (size_t)(n0 + r) * cH + k0 + c) = o;
  } else if (bid < 12288) {
    int blk = bid - 4096;          // cB*cW*cS = 8192
    int b = blk >> 12, w = (blk >> 10) & 3, s = blk & 1023;
    const float* src = cache + ((size_t)((w * cB + b) * cS + s)) * cH;
    u16* dst = kvin + ((size_t)(b * cL + w * cS + s)) * cH;
    float4 v = *(const float4*)(src + t * 4);
    ushort4 o; u16* op = (u16*)&o;
    op[0] = f2u(v.x); op[1] = f2u(v.y); op[2] = f2u(v.z); op[3] = f2u(v.w);
    *(ushort4*)(dst + t * 4) = o;
  } else {
    int r = bid - 12288;           // 0..cB*cS-1
    const float* sp = hidden + (size_t)r * cH;
    float4 x = ((const float4*)sp)[t];
    float s1 = x.x + x.y + x.z + x.w;
    float s2 = x.x * x.x + x.y * x.y + x.z * x.z + x.w * x.w;
    #pragma unroll
    for (int off = 32; off > 0; off >>= 1) {
      s1 += __shfl_down(s1, off);
      s2 += __shfl_down(s2, off);
    }
    int wid = t >> 6, lid = t & 63;
    if (lid == 0) { red[wid] = s1; red[4 + wid] = s2; }
    __syncthreads();
    if (t == 0) {
      float a = red[0] + red[1] + red[2] + red[3];
      float b2 = red[4] + red[5] + red[6] + red[7];
      float mu = a * (1.f / cH);
      float var = b2 * (1.f / cH) - mu * mu;
      if (var < 0.f) var = 0.f;
      red[8] = mu; red[9] = rsqrtf(var + cEPS);
    }
    __syncthreads();
    float mu = red[8], rs = red[9];
    int h0 = t * 4;
    float4 sc = *(const float4*)(scale + h0);
    float4 bi = *(const float4*)(bias + h0);
    int b = r >> 10, s = r & (cS - 1);
    u16* dp = kvin + ((size_t)(b * cL + cW * cS + s)) * cH + h0;
    ushort4 o; u16* op = (u16*)&o;
    op[0] = f2u((x.x - mu) * rs * sc.x + bi.x);
    op[1] = f2u((x.y - mu) * rs * sc.y + bi.y);
    op[2] = f2u((x.z - mu) * rs * sc.z + bi.z);
    op[3] = f2u((x.w - mu) * rs * sc.w + bi.w);
    *(ushort4*)dp = o;
  }
}

// ---------------- MFMA GEMM: C[M,1024] = A(bf16)[M,1024] @ W, Wt=[n][k] bf16 ----------------
// K-loop: m97-style — global_load_lds(16B) direct into linear [128][32] LDS
// tiles, double-buffered, counted vmcnt(4), raw barriers.
// mode 5: fused K|V projection; n0<1024 -> K (mode1), n0>=1024 -> V (mode3).
// mode 1 epilogue now applies RoPE in-register: for a fixed thread, nt and
// nt+2 hold dims d and d+32 of the same head/row (n = n0+wn+nt*16+l15),
// pos = lo & 1023 — identical math to the old rope_b16 pass, minus a kernel.
constexpr int GBM = 128, GBN = 128, TLD = 136;

__global__ __launch_bounds__(256) void mgemm(
    const u16* __restrict__ A, const u16* __restrict__ Wt,
    int a_rpb, int a_base, int a_stride,
    int c_rpb, int mode,
    u16* __restrict__ Cb, u16* __restrict__ Cb2,
    const float* __restrict__ hidden, const float* __restrict__ cachefull,
    const float* __restrict__ gate, const float* __restrict__ lsc,
    float* __restrict__ outp)
{
  __shared__ __align__(16) u16 smem[128 * TLD];

  int t = threadIdx.x;
  int m0 = blockIdx.y * GBM, n0 = blockIdx.x * GBN;
  int wave = t >> 6, lane = t & 63, l15 = lane & 15, quad = lane >> 4;
  int wm = (wave >> 1) * 64, wn = (wave & 1) * 64;

  int sr = t >> 2, sk = (t & 3) * 8;
  int rg0 = m0 + sr, rg1 = rg0 + 64;
  int ab0 = rg0 / a_rpb, ab1 = rg1 / a_rpb;
  const u16* arow0 = A + (size_t)(ab0 * a_stride + a_base + (rg0 - ab0 * a_rpb)) * cH + sk;
  const u16* arow1 = A + (size_t)(ab1 * a_stride + a_base + (rg1 - ab1 * a_rpb)) * cH + sk;
  const u16* wrow0 = Wt + (size_t)(n0 + sr) * cH + sk;
  const u16* wrow1 = Wt + (size_t)(n0 + sr + 64) * cH + sk;

  u16* As0 = smem;
  u16* Bs0 = smem + 8192;
  int wofs = wave * 512;

  f32x4 acc[4][4] = {};

  gl_lds16(arow0, As0 + wofs);
  gl_lds16(arow1, As0 + 2048 + wofs);
  gl_lds16(wrow0, Bs0 + wofs);
  gl_lds16(wrow1, Bs0 + 2048 + wofs);

  constexpr int NK = cH / 32;
  for (int kt = 0; kt < NK; kt++) {
    int cur = kt & 1;
    asm volatile("" ::: "memory");
    __builtin_amdgcn_s_barrier();
    asm volatile("" ::: "memory");
    int nk = kt + 1; if (nk == NK) nk = 0;
    int nko = nk * 32;
    u16* Abn = As0 + (cur ^ 1) * 4096;
    u16* Bbn = Bs0 + (cur ^ 1) * 4096;
    gl_lds16(arow0 + nko, Abn + wofs);
    gl_lds16(arow1 + nko, Abn + 2048 + wofs);
    gl_lds16(wrow0 + nko, Bbn + wofs);
    gl_lds16(wrow1 + nko, Bbn + 2048 + wofs);
    asm volatile("s_waitcnt vmcnt(4)" ::: "memory");
    __builtin_amdgcn_s_barrier();
    asm volatile("" ::: "memory");
    const u16* Ab = As0 + cur * 4096;
    const u16* Bb = Bs0 + cur * 4096;
    s16x8 af[4], bf[4];
    #pragma unroll
    for (int mt = 0; mt < 4; mt++)
      af[mt] = *(const s16x8*)&Ab[(wm + mt * 16 + l15) * 32 + quad * 8];
    #pragma unroll
    for (int nt = 0; nt < 4; nt++)
      bf[nt] = *(const s16x8*)&Bb[(wn + nt * 16 + l15) * 32 + quad * 8];
    #pragma unroll
    for (int mt = 0; mt < 4; mt++)
      #pragma unroll
      for (int nt = 0; nt < 4; nt++)
        acc[mt][nt] = __builtin_amdgcn_mfma_f32_16x16x32_bf16(af[mt], bf[nt], acc[mt][nt], 0, 0, 0);
  }

  int mode_eff = mode;
  u16* Cout = Cb;
  int nbase = n0;
  if (mode == 5) {
    if (n0 < cH) { mode_eff = 1; }
    else { mode_eff = 3; Cout = Cb2; nbase = n0 - cH; }
  }

  if (mode_eff == 1) {
    // fused RoPE: dh0 = l15 (pairs nt0/nt2), dh1 = 16+l15 (pairs nt1/nt3)
    constexpr float RC = 13.287712379549449f / 32.f;   // log2(10000)/32
    float fr0 = exp2f(-(float)l15 * RC);
    float fr1 = exp2f(-(float)(l15 + 16) * RC);
    #pragma unroll
    for (int mt = 0; mt < 4; mt++)
      #pragma unroll
      for (int i = 0; i < 4; i++) {
        int rg = m0 + wm + mt * 16 + quad * 4 + i;
        int bo = rg / c_rpb, lo = rg - bo * c_rpb;
        int pos = lo & (cS - 1);
        float sn0, cs0, sn1, cs1;
        sincosf((float)pos * fr0, &sn0, &cs0);
        sincosf((float)pos * fr1, &sn1, &cs1);
        float v0 = acc[mt][0][i], v1 = acc[mt][1][i];
        float v2 = acc[mt][2][i], v3 = acc[mt][3][i];
        float rr[4];
        rr[0] = v0 * cs0 - v2 * sn0;
        rr[1] = v1 * cs1 - v3 * sn1;
        rr[2] = v0 * sn0 + v2 * cs0;
        rr[3] = v1 * sn1 + v3 * cs1;
        #pragma unroll
        for (int nt = 0; nt < 4; nt++) {
          int n = nbase + wn + nt * 16 + l15;
          int h = n >> 6, d = n & 63;
          Cout[(((size_t)(bo * cNH + h) * c_rpb + lo) * cHD) + d] = f2u(rr[nt]);
        }
      }
  } else if (mode_eff == 3) {
    u16* t2 = smem;
    asm volatile("s_waitcnt vmcnt(0)" ::: "memory");
    __syncthreads();
    #pragma unroll
    for (int mt = 0; mt < 4; mt++)
      #pragma unroll
      for (int nt = 0; nt < 4; nt++) {
        ushort4 o; u16* op = (u16*)&o;
        #pragma unroll
        for (int i = 0; i < 4; i++) op[i] = f2u(acc[mt][nt][i]);
        *(ushort4*)&t2[(size_t)(wn + nt * 16 + l15) * TLD + wm + mt * 16 + quad * 4] = o;
      }
    __syncthreads();
    int n_l = t >> 1, mh = (t & 1) * 64;
    int bo = m0 / c_rpb;
    int lo = m0 - bo * c_rpb + mh;
    int n = nbase + n_l, h = n >> 6, d = n & 63;
    u16* dst = Cout + ((size_t)(bo * cNH + h) * cHD + d) * (size_t)c_rpb + lo;
    #pragma unroll
    for (int j = 0; j < 8; j++)
      *(uint4*)(dst + j * 8) = *(const uint4*)&t2[(size_t)n_l * TLD + mh + j * 8];
  } else {
    float gv[4], lv[4];
    #pragma unroll
    for (int nt = 0; nt < 4; nt++) {
      int n = n0 + wn + nt * 16 + l15;
      gv[nt] = 1.f / (1.f + __expf(-gate[n]));
      lv[nt] = lsc[n];
    }
    #pragma unroll
    for (int mt = 0; mt < 4; mt++)
      #pragma unroll
      for (int i = 0; i < 4; i++) {
        int rg = m0 + wm + mt * 16 + quad * 4 + i;
        size_t rbase = (size_t)rg * cH;
        #pragma unroll
        for (int nt = 0; nt < 4; nt++) {
          int n = n0 + wn + nt * 16 + l15;
          float hid = hidden[rbase + n];
          float cr = cachefull[(size_t)3 * cB * cS * cH + rbase + n];
          outp[rbase + n] = hid + lv[nt] * (gv[nt] * acc[mt][nt][i] + (1.f - gv[nt]) * cr);
        }
      }
  }
}

// ---------------- MFMA flash attention, 5-way split-K ----------------
// 2 q-tiles per wave, launch_bounds(256,3) (no-spill operating point, r8).
// KSPLIT=5: grid 1280 blocks at 3/CU (768 resident) -> 83% fill vs r8's 67%
// (1024 blocks), 16 key-tiles per block instead of 20.
constexpr int ACK = 64;
constexpr int PLD = 72;
constexpr int KSPLIT = 5;
constexpr int KS = cL / KSPLIT;      // 1024 keys per split
constexpr int NIT = KS / ACK;        // 16 tiles
constexpr int NRB = cB * cNH * cS;   // rows per split (32768)

__global__ __launch_bounds__(256, 3) void attn_mfma(
    const u16* __restrict__ Q, const u16* __restrict__ K, const u16* __restrict__ Vt,
    float* __restrict__ o0, float* __restrict__ o1,
    float* __restrict__ o2, float* __restrict__ o3, float* __restrict__ o4,
    float* __restrict__ mlbuf)
{
  __shared__ __align__(16) u16 kls[2][ACK * cHD];     // 16 KB
  __shared__ u16 pbuf[4][2][16 * PLD];                // 18.4 KB

  int t = threadIdx.x;
  int wave = t >> 6, lane = t & 63;
  int l15 = lane & 15, quad = lane >> 4;
  int qt = blockIdx.x, h = blockIdx.y;
  int bz = blockIdx.z;
  int b = bz & (cB - 1), split = bz >> 1;
  int q0a = qt * 128 + wave * 16;
  int q0b = q0a + 64;
  int kbase = split * KS;

  const u16* qpa = Q + ((size_t)(b * cNH + h) * cS + q0a) * cHD;
  const u16* qpb = qpa + (size_t)64 * cHD;
  const char* kp = (const char*)(K + ((size_t)(b * cNH + h) * cL + kbase) * cHD);
  const u16* vp = Vt + (size_t)(b * cNH + h) * cHD * cL + kbase;
  u16* pwA = &pbuf[wave][0][0];
  u16* pwB = &pbuf[wave][1][0];

  int P0 = wave * 1024 + lane * 16;
  int P1 = P0 + 4096;
  int s0 = P0 ^ (((P0 >> 7) & 7) << 4);
  int s1 = P1 ^ (((P1 >> 7) & 7) << 4);
  int fsw0 = (quad * 16) ^ ((l15 & 7) << 4);
  int fsw1 = (64 + quad * 16) ^ ((l15 & 7) << 4);

  s16x8 qa0 = ld_frag(qpa + (size_t)l15 * cHD + quad * 8);
  s16x8 qa1 = ld_frag(qpa + (size_t)l15 * cHD + 32 + quad * 8);
  s16x8 qb0f = ld_frag(qpb + (size_t)l15 * cHD + quad * 8);
  s16x8 qb1f = ld_frag(qpb + (size_t)l15 * cHD + 32 + quad * 8);

  gl_lds16((const u16*)(kp + s0), (u16*)((char*)&kls[0][0] + wave * 1024));
  gl_lds16((const u16*)(kp + s1), (u16*)((char*)&kls[0][0] + 4096 + wave * 1024));

  f32x4 oacc[2][4] = {};
  float mrowA[4], lrowA[4], mrowB[4], lrowB[4];
  #pragma unroll
  for (int i = 0; i < 4; i++) {
    mrowA[i] = -1e30f; lrowA[i] = 0.f;
    mrowB[i] = -1e30f; lrowB[i] = 0.f;
  }

  constexpr float SCL = 0.125f * 1.4426950408889634f;

  for (int kt = 0; kt < NIT; kt++) {
    int cur = kt & 1;
    uint4 v01[4];
    #pragma unroll
    for (int dt = 0; dt < 2; dt++) {
      const u16* vr = vp + (size_t)(dt * 16 + l15) * cL + kt * ACK;
      v01[2 * dt]     = *(const uint4*)(vr + quad * 8);
      v01[2 * dt + 1] = *(const uint4*)(vr + 32 + quad * 8);
    }
    asm volatile("" ::: "memory");
    __builtin_amdgcn_s_barrier();
    asm volatile("" ::: "memory");
    int nk = kt + 1; if (nk == NIT) nk = 0;
    const char* kn = kp + (size_t)nk * (ACK * cHD * 2);
    gl_lds16((const u16*)(kn + s0), (u16*)((char*)&kls[cur ^ 1][0] + wave * 1024));
    gl_lds16((const u16*)(kn + s1), (u16*)((char*)&kls[cur ^ 1][0] + 4096 + wave * 1024));
    asm volatile("s_waitcnt vmcnt(6)" ::: "memory");
    __builtin_amdgcn_s_barrier();
    asm volatile("" ::: "memory");
    const char* kc = (const char*)&kls[cur][0];
    f32x4 scA[4], scB[4];
    __builtin_amdgcn_s_setprio(1);
    #pragma unroll
    for (int nt = 0; nt < 4; nt++) {
      s16x8 kf0 = *(const s16x8*)(kc + (nt * 16 + l15) * 128 + fsw0);
      s16x8 kf1 = *(const s16x8*)(kc + (nt * 16 + l15) * 128 + fsw1);
      f32x4 a = {};
      a = __builtin_amdgcn_mfma_f32_16x16x32_bf16(qa0, kf0, a, 0, 0, 0);
      a = __builtin_amdgcn_mfma_f32_16x16x32_bf16(qa1, kf1, a, 0, 0, 0);
      scA[nt] = a * SCL;
      f32x4 c = {};
      c = __builtin_amdgcn_mfma_f32_16x16x32_bf16(qb0f, kf0, c, 0, 0, 0);
      c = __builtin_amdgcn_mfma_f32_16x16x32_bf16(qb1f, kf1, c, 0, 0, 0);
      scB[nt] = c * SCL;
    }
    __builtin_amdgcn_s_setprio(0);
    float mxA[4], mxB[4];
    #pragma unroll
    for (int i = 0; i < 4; i++) {
      mxA[i] = fmaxf(fmaxf(scA[0][i], scA[1][i]), fmaxf(scA[2][i], scA[3][i]));
      mxB[i] = fmaxf(fmaxf(scB[0][i], scB[1][i]), fmaxf(scB[2][i], scB[3][i]));
    }
    #pragma unroll
    for (int i = 0; i < 4; i++) {
      mxA[i] = dpp_fmax<0xB1>(mxA[i]);  mxB[i] = dpp_fmax<0xB1>(mxB[i]);
      mxA[i] = dpp_fmax<0x4E>(mxA[i]);  mxB[i] = dpp_fmax<0x4E>(mxB[i]);
      mxA[i] = dpp_fmax<0x141>(mxA[i]); mxB[i] = dpp_fmax<0x141>(mxB[i]);
      mxA[i] = dpp_fmax<0x140>(mxA[i]); mxB[i] = dpp_fmax<0x140>(mxB[i]);
    }
    bool needA = (mxA[0] > mrowA[0]) | (mxA[1] > mrowA[1]) |
                 (mxA[2] > mrowA[2]) | (mxA[3] > mrowA[3]);
    if (__any(needA)) {
      float alpha[4];
      #pragma unroll
      for (int i = 0; i < 4; i++) {
        float mn = fmaxf(mrowA[i], mxA[i]);
        alpha[i] = exp2f(mrowA[i] - mn);
        mrowA[i] = mn;
        lrowA[i] *= alpha[i];
      }
      #pragma unroll
      for (int dt = 0; dt < 4; dt++)
        #pragma unroll
        for (int i = 0; i < 4; i++) oacc[0][dt][i] *= alpha[i];
    }
    bool needB = (mxB[0] > mrowB[0]) | (mxB[1] > mrowB[1]) |
                 (mxB[2] > mrowB[2]) | (mxB[3] > mrowB[3]);
    if (__any(needB)) {
      float alpha[4];
      #pragma unroll
      for (int i = 0; i < 4; i++) {
        float mn = fmaxf(mrowB[i], mxB[i]);
        alpha[i] = exp2f(mrowB[i] - mn);
        mrowB[i] = mn;
        lrowB[i] *= alpha[i];
      }
      #pragma unroll
      for (int dt = 0; dt < 4; dt++)
        #pragma unroll
        for (int i = 0; i < 4; i++) oacc[1][dt][i] *= alpha[i];
    }
    {
      float ps[4] = {};
      #pragma unroll
      for (int nt = 0; nt < 4; nt++)
        #pragma unroll
        for (int i = 0; i < 4; i++) {
          float p = exp2f(scA[nt][i] - mrowA[i]);
          ps[i] += p;
          pwA[(quad * 4 + i) * PLD + nt * 16 + l15] = f2u_rt(p);
        }
      #pragma unroll
      for (int i = 0; i < 4; i++) lrowA[i] += ps[i];
    }
    uint4 v23[4];
    #pragma unroll
    for (int dt = 2; dt < 4; dt++) {
      const u16* vr = vp + (size_t)(dt * 16 + l15) * cL + kt * ACK;
      v23[2 * (dt - 2)]     = *(const uint4*)(vr + quad * 8);
      v23[2 * (dt - 2) + 1] = *(const uint4*)(vr + 32 + quad * 8);
    }
    {
      float ps[4] = {};
      #pragma unroll
      for (int nt = 0; nt < 4; nt++)
        #pragma unroll
        for (int i = 0; i < 4; i++) {
          float p = exp2f(scB[nt][i] - mrowB[i]);
          ps[i] += p;
          pwB[(quad * 4 + i) * PLD + nt * 16 + l15] = f2u_rt(p);
        }
      #pragma unroll
      for (int i = 0; i < 4; i++) lrowB[i] += ps[i];
    }
    s16x8 pfA0 = *(const s16x8*)&pwA[l15 * PLD + quad * 8];
    s16x8 pfA1 = *(const s16x8*)&pwA[l15 * PLD + 32 + quad * 8];
    s16x8 pfB0 = *(const s16x8*)&pwB[l15 * PLD + quad * 8];
    s16x8 pfB1 = *(const s16x8*)&pwB[l15 * PLD + 32 + quad * 8];
    __builtin_amdgcn_s_setprio(1);
    #pragma unroll
    for (int dt = 0; dt < 2; dt++) {
      oacc[0][dt] = __builtin_amdgcn_mfma_f32_16x16x32_bf16(pfA0, u4_frag(v01[2 * dt]), oacc[0][dt], 0, 0, 0);
      oacc[0][dt] = __builtin_amdgcn_mfma_f32_16x16x32_bf16(pfA1, u4_frag(v01[2 * dt + 1]), oacc[0][dt], 0, 0, 0);
      oacc[1][dt] = __builtin_amdgcn_mfma_f32_16x16x32_bf16(pfB0, u4_frag(v01[2 * dt]), oacc[1][dt], 0, 0, 0);
      oacc[1][dt] = __builtin_amdgcn_mfma_f32_16x16x32_bf16(pfB1, u4_frag(v01[2 * dt + 1]), oacc[1][dt], 0, 0, 0);
    }
    #pragma unroll
    for (int dt = 2; dt < 4; dt++) {
      int vi = 2 * (dt - 2);
      oacc[0][dt] = __builtin_amdgcn_mfma_f32_16x16x32_bf16(pfA0, u4_frag(v23[vi]), oacc[0][dt], 0, 0, 0);
      oacc[0][dt] = __builtin_amdgcn_mfma_f32_16x16x32_bf16(pfA1, u4_frag(v23[vi + 1]), oacc[0][dt], 0, 0, 0);
      oacc[1][dt] = __builtin_amdgcn_mfma_f32_16x16x32_bf16(pfB0, u4_frag(v23[vi]), oacc[1][dt], 0, 0, 0);
      oacc[1][dt] = __builtin_amdgcn_mfma_f32_16x16x32_bf16(pfB1, u4_frag(v23[vi + 1]), oacc[1][dt], 0, 0, 0);
    }
    __builtin_amdgcn_s_setprio(0);
  }
  #pragma unroll
  for (int off = 1; off < 16; off <<= 1)
    #pragma unroll
    for (int i = 0; i < 4; i++) {
      lrowA[i] += __shfl_xor(lrowA[i], off);
      lrowB[i] += __shfl_xor(lrowB[i], off);
    }
  float* ob = (split == 0) ? o0 : (split == 1) ? o1 : (split == 2) ? o2 :
              (split == 3) ? o3 : o4;
  #pragma unroll
  for (int x = 0; x < 2; x++) {
    int qbase = x ? q0b : q0a;
    #pragma unroll
    for (int i = 0; i < 4; i++) {
      int q = qbase + quad * 4 + i;
      size_t Rl = (size_t)(b * cNH + h) * cS + q;
      float* orow = ob + Rl * cHD;
      #pragma unroll
      for (int dt = 0; dt < 4; dt++)
        orow[dt * 16 + l15] = oacc[x][dt][i];
      if (l15 == 0) {
        mlbuf[((size_t)split * NRB + Rl) * 2]     = x ? mrowB[i] : mrowA[i];
        mlbuf[((size_t)split * NRB + Rl) * 2 + 1] = x ? lrowB[i] : lrowA[i];
      }
    }
  }
}

// ---------------- split-K merge: combine five softmax partials -> bf16 ctx ----------------
__global__ __launch_bounds__(256) void attn_merge(
    const float* __restrict__ o0, const float* __restrict__ o1,
    const float* __restrict__ o2, const float* __restrict__ o3,
    const float* __restrict__ o4,
    const float* __restrict__ mlbuf, u16* __restrict__ ctx)
{
  int t = threadIdx.x;
  int R = blockIdx.x * 4 + (t >> 6);   // (b*cNH+h)*cS + q
  int d = t & 63;
  float ms[KSPLIT], ls[KSPLIT];
  float m = -1e30f;
  #pragma unroll
  for (int s = 0; s < KSPLIT; s++) {
    ms[s] = mlbuf[((size_t)s * NRB + R) * 2];
    ls[s] = mlbuf[((size_t)s * NRB + R) * 2 + 1];
    m = fmaxf(m, ms[s]);
  }
  const float* ops[KSPLIT] = {o0, o1, o2, o3, o4};
  float num = 0.f, den = 0.f;
  #pragma unroll
  for (int s = 0; s < KSPLIT; s++) {
    float a = exp2f(ms[s] - m);
    num += ops[s][(size_t)R * cHD + d] * a;
    den += ls[s] * a;
  }
  float val = num / den;
  int q = R & (cS - 1), h = (R >> 10) & 15, b = R >> 14;
  ctx[((size_t)b * cS + q) * cH + h * cHD + d] = f2u(val);
}

extern "C" void kernel_launch(void* const* d_in, const int* in_sizes, int n_in,
                              void* d_out, int out_size, void* d_ws, size_t ws_size,
                              hipStream_t stream)
{
  const float* hidden = (const float*)d_in[0];
  const float* cache  = (const float*)d_in[1];
  const float* ln_s   = (const float*)d_in[2];
  const float* ln_b   = (const float*)d_in[3];
  const float* Wq     = (const float*)d_in[4];
  const float* Wk     = (const float*)d_in[5];
  const float* Wv     = (const float*)d_in[6];
  const float* Wo     = (const float*)d_in[7];
  const float* gate   = (const float*)d_in[8];
  const float* lsc    = (const float*)d_in[9];
  float* outp = (float*)d_out;

  // ws: kvin 20.97M | vt 20.97M | opart(splits 0,1) 16.78M  (~58.7 MB)
  u16* kvin = (u16*)d_ws;
  u16* vt   = kvin + (size_t)cB * cL * cH;
  float* opart = (float*)(vt + (size_t)cB * cL * cH);
  float* o0 = opart;
  float* o1 = opart + (size_t)cB * cNH * cS * cHD;          // +8.39MB
  // aliases into kvin (dead rows by the time these are written):
  u16* qb  = kvin;                                // [0, 4.19M) written by Q GEMM (last kvin reader)
  u16* ctx = kvin + (size_t)2 * 1024 * 1024;      // [4.19M, 8.39M) written by attn_merge
  float* o2 = (float*)(kvin + (size_t)4 * 1024 * 1024);   // bytes [8.39M, 16.78M)
  float* mlbuf = (float*)(kvin + (size_t)8 * 1024 * 1024);// bytes [16.78M, 18.09M), 5 splits
  // split-3 opart in d_out output region [0, 8.39M): written by attn, read by
  // merge, then overwritten by the step-7 GEMM epilogue.
  float* o3 = outp;
  // split-4 opart at d_out bytes [29.36M, 37.75M): starts where kb ends;
  // covers the free gap [29.36,33.55) + Wt_q..Wt_v [33.55,39.84) — all dead
  // after the Q GEMM (which precedes attn).  Wt_o at [39.84,41.94) intact.
  float* o4 = outp + (size_t)7 * cB * cS * cH / 2;
  // scratch parked in d_out (overwritten by memcpy/final-LN at the end):
  u16* kb = (u16*)(outp + (size_t)cB * cS * cH);
  u16* Wt = (u16*)(outp + (size_t)(1 + 3) * cB * cS * cH);
  u16* Wt_q = Wt;
  u16* Wt_k = Wt + (size_t)cH * cH;
  u16* Wt_o = Wt + (size_t)3 * cH * cH;

  // 1) prep: weight transpose + cache->kvin + pre-norm, one launch
  prep<<<14336, 256, 0, stream>>>(Wq, Wk, Wv, Wo, Wt, cache, kvin,
                                  hidden, ln_s, ln_b);

  // 2) fused K|V projection (RoPE fused into K epilogue), then Q (RoPE fused)
  mgemm<<<dim3(16, (cB * cL) / GBM), 256, 0, stream>>>(
      kvin, Wt_k, cL, 0, cL, cL, 5, kb, vt, nullptr, nullptr, nullptr, nullptr, nullptr);
  mgemm<<<dim3(8, (cB * cS) / GBM), 256, 0, stream>>>(
      kvin, Wt_q, cS, cW * cS, cL, cS, 1, qb, nullptr, nullptr, nullptr, nullptr, nullptr, nullptr);

  // 3) 5-way split-K MFMA flash attention (2 q-tiles/wave) -> partials -> merge
  attn_mfma<<<dim3(cS / 128, cNH, cB * KSPLIT), 256, 0, stream>>>(
      qb, kb, vt, o0, o1, o2, o3, o4, mlbuf);
  attn_merge<<<(cB * cNH * cS) / 4, 256, 0, stream>>>(o0, o1, o2, o3, o4, mlbuf, ctx);

  // 4) ctx @ Wo with fused gated residual -> output f32
  mgemm<<<dim3(8, (cB * cS) / GBM), 256, 0, stream>>>(
      ctx, Wt_o, cB * cS, 0, cB * cS, cB * cS, 2, nullptr, nullptr,
      hidden, cache, gate, lsc, outp);

  // 5) new_cache[0:3] = cache[1:4]
  hipMemcpyAsync(outp + (size_t)cB * cS * cH, cache + (size_t)cB * cS * cH,
                 (size_t)(cW - 1) * cB * cS * cH * sizeof(float),
                 hipMemcpyDeviceToDevice, stream);
  // 6) final layernorm -> new_cache slot 3
  ln_f32<<<cB * cS, 256, 0, stream>>>(outp, outp + (size_t)cW * cB * cS * cH, ln_s, ln_b);
}

// Round 10
// 365.816 us; speedup vs baseline: 1.1996x; 1.0210x over previous
//
#include <hip/hip_runtime.h>
#include <math.h>

typedef unsigned short u16;

constexpr int cB = 2;
constexpr int cS = 1024;
constexpr int cH = 1024;
constexpr int cNH = 16;
constexpr int cHD = 64;
constexpr int cW = 4;
constexpr int cL = (cW + 1) * cS; // 5120
constexpr float cEPS = 1e-5f;

typedef short s16x8 __attribute__((ext_vector_type(8)));   // 8 bf16 (4 VGPRs)
typedef float f32x4 __attribute__((ext_vector_type(4)));   // MFMA C/D

__device__ __forceinline__ float u2f(u16 u) {
  union { unsigned int i; float f; } x; x.i = ((unsigned int)u) << 16; return x.f;
}
__device__ __forceinline__ u16 f2u(float f) {
  union { float f; unsigned int i; } x; x.f = f;
  unsigned int i = x.i;
  i += 0x7fffu + ((i >> 16) & 1u); // RNE
  return (u16)(i >> 16);
}
// fast path: native v_cvt bf16 (RNE), 1 VALU op
__device__ __forceinline__ u16 f2u_rt(float f) {
  union { __bf16 b; u16 u; } c; c.b = (__bf16)f; return c.u;
}
__device__ __forceinline__ s16x8 ld_frag(const u16* p) {
  uint4 v = *(const uint4*)p;
  union { uint4 u; s16x8 s; } c; c.u = v; return c.s;
}
__device__ __forceinline__ s16x8 u4_frag(uint4 v) {
  union { uint4 u; s16x8 s; } c; c.u = v; return c.s;
}
// async 16B global -> LDS (dest = wave-uniform base + lane*16)
__device__ __forceinline__ void gl_lds16(const u16* g, u16* l) {
  __builtin_amdgcn_global_load_lds(
      (const __attribute__((address_space(1))) unsigned int*)g,
      (__attribute__((address_space(3))) unsigned int*)l, 16, 0, 0);
}
// VALU-pipe cross-lane fmax via DPP (ctrl must be a literal -> template param)
template <int CTRL>
__device__ __forceinline__ float dpp_fmax(float x) {
  union { float f; int i; } a, r;
  a.f = x;
  r.i = __builtin_amdgcn_update_dpp(a.i, a.i, CTRL, 0xF, 0xF, true);
  return fmaxf(x, r.f);
}

// ---------------- LayerNorm f32 -> f32 (final LN) ----------------
__global__ __launch_bounds__(256) void ln_f32(
    const float* __restrict__ src, float* __restrict__ dst,
    const float* __restrict__ scale, const float* __restrict__ bias)
{
  int r = blockIdx.x;
  int t = threadIdx.x;
  const float* sp = src + (size_t)r * cH;
  float4 x = ((const float4*)sp)[t];
  float s1 = x.x + x.y + x.z + x.w;
  float s2 = x.x * x.x + x.y * x.y + x.z * x.z + x.w * x.w;
  #pragma unroll
  for (int off = 32; off > 0; off >>= 1) {
    s1 += __shfl_down(s1, off);
    s2 += __shfl_down(s2, off);
  }
  __shared__ float w1[4], w2[4];
  __shared__ float stat[2];
  int wid = t >> 6, lid = t & 63;
  if (lid == 0) { w1[wid] = s1; w2[wid] = s2; }
  __syncthreads();
  if (t == 0) {
    float a = w1[0] + w1[1] + w1[2] + w1[3];
    float b = w2[0] + w2[1] + w2[2] + w2[3];
    float mu = a * (1.f / cH);
    float var = b * (1.f / cH) - mu * mu;
    if (var < 0.f) var = 0.f;
    stat[0] = mu; stat[1] = rsqrtf(var + cEPS);
  }
  __syncthreads();
  float mu = stat[0], rs = stat[1];
  int h0 = t * 4;
  float4 sc = *(const float4*)(scale + h0);
  float4 bi = *(const float4*)(bias + h0);
  float4 o;
  o.x = (x.x - mu) * rs * sc.x + bi.x;
  o.y = (x.y - mu) * rs * sc.y + bi.y;
  o.z = (x.z - mu) * rs * sc.z + bi.z;
  o.w = (x.w - mu) * rs * sc.w + bi.w;
  *(float4*)(dst + (size_t)r * cH + h0) = o;
}

// ---------------- prep: wtrans(4 mats) + cache2kv + ln_bf16, one launch ----------------
__global__ __launch_bounds__(256) void prep(
    const float* __restrict__ W0, const float* __restrict__ W1,
    const float* __restrict__ W2, const float* __restrict__ W3,
    u16* __restrict__ Wt,
    const float* __restrict__ cache, u16* __restrict__ kvin,
    const float* __restrict__ hidden,
    const float* __restrict__ scale, const float* __restrict__ bias)
{
  __shared__ float tile[32][33];
  __shared__ float red[10];
  int t = threadIdx.x;
  int bid = blockIdx.x;
  if (bid < 4096) {
    int mat = bid >> 10;
    int k0 = ((bid >> 5) & 31) * 32, n0 = (bid & 31) * 32;
    const float* W = (mat == 0) ? W0 : (mat == 1) ? W1 : (mat == 2) ? W2 : W3;
    u16* out = Wt + (size_t)mat * cH * cH;
    int r = t >> 3, c = (t & 7) * 4;
    float4 v = *(const float4*)(W + (size_t)(k0 + r) * cH + n0 + c);
    tile[r][c] = v.x; tile[r][c + 1] = v.y; tile[r][c + 2] = v.z; tile[r][c + 3] = v.w;
    __syncthreads();
    ushort4 o; u16* op = (u16*)&o;
    #pragma unroll
    for (int j = 0; j < 4; j++) op[j] = f2u(tile[c + j][r]);
    *(ushort4*)(out + (size_t)(n0 + r) * cH + k0 + c) = o;
  } else if (bid < 12288) {
    int blk = bid - 4096;          // cB*cW*cS = 8192
    int b = blk >> 12, w = (blk >> 10) & 3, s = blk & 1023;
    const float* src = cache + ((size_t)((w * cB + b) * cS + s)) * cH;
    u16* dst = kvin + ((size_t)(b * cL + w * cS + s)) * cH;
    float4 v = *(const float4*)(src + t * 4);
    ushort4 o; u16* op = (u16*)&o;
    op[0] = f2u(v.x); op[1] = f2u(v.y); op[2] = f2u(v.z); op[3] = f2u(v.w);
    *(ushort4*)(dst + t * 4) = o;
  } else {
    int r = bid - 12288;           // 0..cB*cS-1
    const float* sp = hidden + (size_t)r * cH;
    float4 x = ((const float4*)sp)[t];
    float s1 = x.x + x.y + x.z + x.w;
    float s2 = x.x * x.x + x.y * x.y + x.z * x.z + x.w * x.w;
    #pragma unroll
    for (int off = 32; off > 0; off >>= 1) {
      s1 += __shfl_down(s1, off);
      s2 += __shfl_down(s2, off);
    }
    int wid = t >> 6, lid = t & 63;
    if (lid == 0) { red[wid] = s1; red[4 + wid] = s2; }
    __syncthreads();
    if (t == 0) {
      float a = red[0] + red[1] + red[2] + red[3];
      float b2 = red[4] + red[5] + red[6] + red[7];
      float mu = a * (1.f / cH);
      float var = b2 * (1.f / cH) - mu * mu;
      if (var < 0.f) var = 0.f;
      red[8] = mu; red[9] = rsqrtf(var + cEPS);
    }
    __syncthreads();
    float mu = red[8], rs = red[9];
    int h0 = t * 4;
    float4 sc = *(const float4*)(scale + h0);
    float4 bi = *(const float4*)(bias + h0);
    int b = r >> 10, s = r & (cS - 1);
    u16* dp = kvin + ((size_t)(b * cL + cW * cS + s)) * cH + h0;
    ushort4 o; u16* op = (u16*)&o;
    op[0] = f2u((x.x - mu) * rs * sc.x + bi.x);
    op[1] = f2u((x.y - mu) * rs * sc.y + bi.y);
    op[2] = f2u((x.z - mu) * rs * sc.z + bi.z);
    op[3] = f2u((x.w - mu) * rs * sc.w + bi.w);
    *(ushort4*)dp = o;
  }
}

// ---------------- MFMA GEMM (m97 staging; RoPE fused into mode-1 epilogue) ----------------
constexpr int GBM = 128, GBN = 128, TLD = 136;

__global__ __launch_bounds__(256) void mgemm(
    const u16* __restrict__ A, const u16* __restrict__ Wt,
    int a_rpb, int a_base, int a_stride,
    int c_rpb, int mode,
    u16* __restrict__ Cb, u16* __restrict__ Cb2,
    const float* __restrict__ hidden, const float* __restrict__ cachefull,
    const float* __restrict__ gate, const float* __restrict__ lsc,
    float* __restrict__ outp)
{
  __shared__ __align__(16) u16 smem[128 * TLD];

  int t = threadIdx.x;
  int m0 = blockIdx.y * GBM, n0 = blockIdx.x * GBN;
  int wave = t >> 6, lane = t & 63, l15 = lane & 15, quad = lane >> 4;
  int wm = (wave >> 1) * 64, wn = (wave & 1) * 64;

  int sr = t >> 2, sk = (t & 3) * 8;
  int rg0 = m0 + sr, rg1 = rg0 + 64;
  int ab0 = rg0 / a_rpb, ab1 = rg1 / a_rpb;
  const u16* arow0 = A + (size_t)(ab0 * a_stride + a_base + (rg0 - ab0 * a_rpb)) * cH + sk;
  const u16* arow1 = A + (size_t)(ab1 * a_stride + a_base + (rg1 - ab1 * a_rpb)) * cH + sk;
  const u16* wrow0 = Wt + (size_t)(n0 + sr) * cH + sk;
  const u16* wrow1 = Wt + (size_t)(n0 + sr + 64) * cH + sk;

  u16* As0 = smem;
  u16* Bs0 = smem + 8192;
  int wofs = wave * 512;

  f32x4 acc[4][4] = {};

  gl_lds16(arow0, As0 + wofs);
  gl_lds16(arow1, As0 + 2048 + wofs);
  gl_lds16(wrow0, Bs0 + wofs);
  gl_lds16(wrow1, Bs0 + 2048 + wofs);

  constexpr int NK = cH / 32;
  for (int kt = 0; kt < NK; kt++) {
    int cur = kt & 1;
    asm volatile("" ::: "memory");
    __builtin_amdgcn_s_barrier();
    asm volatile("" ::: "memory");
    int nk = kt + 1; if (nk == NK) nk = 0;
    int nko = nk * 32;
    u16* Abn = As0 + (cur ^ 1) * 4096;
    u16* Bbn = Bs0 + (cur ^ 1) * 4096;
    gl_lds16(arow0 + nko, Abn + wofs);
    gl_lds16(arow1 + nko, Abn + 2048 + wofs);
    gl_lds16(wrow0 + nko, Bbn + wofs);
    gl_lds16(wrow1 + nko, Bbn + 2048 + wofs);
    asm volatile("s_waitcnt vmcnt(4)" ::: "memory");
    __builtin_amdgcn_s_barrier();
    asm volatile("" ::: "memory");
    const u16* Ab = As0 + cur * 4096;
    const u16* Bb = Bs0 + cur * 4096;
    s16x8 af[4], bf[4];
    #pragma unroll
    for (int mt = 0; mt < 4; mt++)
      af[mt] = *(const s16x8*)&Ab[(wm + mt * 16 + l15) * 32 + quad * 8];
    #pragma unroll
    for (int nt = 0; nt < 4; nt++)
      bf[nt] = *(const s16x8*)&Bb[(wn + nt * 16 + l15) * 32 + quad * 8];
    #pragma unroll
    for (int mt = 0; mt < 4; mt++)
      #pragma unroll
      for (int nt = 0; nt < 4; nt++)
        acc[mt][nt] = __builtin_amdgcn_mfma_f32_16x16x32_bf16(af[mt], bf[nt], acc[mt][nt], 0, 0, 0);
  }

  int mode_eff = mode;
  u16* Cout = Cb;
  int nbase = n0;
  if (mode == 5) {
    if (n0 < cH) { mode_eff = 1; }
    else { mode_eff = 3; Cout = Cb2; nbase = n0 - cH; }
  }

  if (mode_eff == 1) {
    // fused RoPE: dh0 = l15 (pairs nt0/nt2), dh1 = 16+l15 (pairs nt1/nt3)
    constexpr float RC = 13.287712379549449f / 32.f;   // log2(10000)/32
    float fr0 = exp2f(-(float)l15 * RC);
    float fr1 = exp2f(-(float)(l15 + 16) * RC);
    #pragma unroll
    for (int mt = 0; mt < 4; mt++)
      #pragma unroll
      for (int i = 0; i < 4; i++) {
        int rg = m0 + wm + mt * 16 + quad * 4 + i;
        int bo = rg / c_rpb, lo = rg - bo * c_rpb;
        int pos = lo & (cS - 1);
        float sn0, cs0, sn1, cs1;
        sincosf((float)pos * fr0, &sn0, &cs0);
        sincosf((float)pos * fr1, &sn1, &cs1);
        float v0 = acc[mt][0][i], v1 = acc[mt][1][i];
        float v2 = acc[mt][2][i], v3 = acc[mt][3][i];
        float rr[4];
        rr[0] = v0 * cs0 - v2 * sn0;
        rr[1] = v1 * cs1 - v3 * sn1;
        rr[2] = v0 * sn0 + v2 * cs0;
        rr[3] = v1 * sn1 + v3 * cs1;
        #pragma unroll
        for (int nt = 0; nt < 4; nt++) {
          int n = nbase + wn + nt * 16 + l15;
          int h = n >> 6, d = n & 63;
          Cout[(((size_t)(bo * cNH + h) * c_rpb + lo) * cHD) + d] = f2u(rr[nt]);
        }
      }
  } else if (mode_eff == 3) {
    u16* t2 = smem;
    asm volatile("s_waitcnt vmcnt(0)" ::: "memory");
    __syncthreads();
    #pragma unroll
    for (int mt = 0; mt < 4; mt++)
      #pragma unroll
      for (int nt = 0; nt < 4; nt++) {
        ushort4 o; u16* op = (u16*)&o;
        #pragma unroll
        for (int i = 0; i < 4; i++) op[i] = f2u(acc[mt][nt][i]);
        *(ushort4*)&t2[(size_t)(wn + nt * 16 + l15) * TLD + wm + mt * 16 + quad * 4] = o;
      }
    __syncthreads();
    int n_l = t >> 1, mh = (t & 1) * 64;
    int bo = m0 / c_rpb;
    int lo = m0 - bo * c_rpb + mh;
    int n = nbase + n_l, h = n >> 6, d = n & 63;
    u16* dst = Cout + ((size_t)(bo * cNH + h) * cHD + d) * (size_t)c_rpb + lo;
    #pragma unroll
    for (int j = 0; j < 8; j++)
      *(uint4*)(dst + j * 8) = *(const uint4*)&t2[(size_t)n_l * TLD + mh + j * 8];
  } else {
    float gv[4], lv[4];
    #pragma unroll
    for (int nt = 0; nt < 4; nt++) {
      int n = n0 + wn + nt * 16 + l15;
      gv[nt] = 1.f / (1.f + __expf(-gate[n]));
      lv[nt] = lsc[n];
    }
    #pragma unroll
    for (int mt = 0; mt < 4; mt++)
      #pragma unroll
      for (int i = 0; i < 4; i++) {
        int rg = m0 + wm + mt * 16 + quad * 4 + i;
        size_t rbase = (size_t)rg * cH;
        #pragma unroll
        for (int nt = 0; nt < 4; nt++) {
          int n = n0 + wn + nt * 16 + l15;
          float hid = hidden[rbase + n];
          float cr = cachefull[(size_t)3 * cB * cS * cH + rbase + n];
          outp[rbase + n] = hid + lv[nt] * (gv[nt] * acc[mt][nt][i] + (1.f - gv[nt]) * cr);
        }
      }
  }
}

// ---------------- MFMA flash attention, 3-way split-K (perfect residency) ----------------
// 2 q-tiles per wave, launch_bounds(256,3).  Grid (8,16,6) = 768 blocks =
// 256 CU x 3 blocks: exactly ONE residency round, zero scheduling tail
// (r9's 1280 blocks on 768 slots = 83% fill was the occupancy cap).
// Splits carry 27/27/26 key-tiles (80 total) — 4% imbalance vs 33% idle.
constexpr int ACK = 64;
constexpr int PLD = 72;
constexpr int KSPLIT = 3;
constexpr int SPLT_T = 27;           // tiles in splits 0,1 (split 2: 26)
constexpr int NRB = cB * cNH * cS;   // rows per split (32768)

__global__ __launch_bounds__(256, 3) void attn_mfma(
    const u16* __restrict__ Q, const u16* __restrict__ K, const u16* __restrict__ Vt,
    float* __restrict__ o0, float* __restrict__ o1, float* __restrict__ o2,
    float* __restrict__ mlbuf)
{
  __shared__ __align__(16) u16 kls[2][ACK * cHD];     // 16 KB
  __shared__ u16 pbuf[4][2][16 * PLD];                // 18.4 KB

  int t = threadIdx.x;
  int wave = t >> 6, lane = t & 63;
  int l15 = lane & 15, quad = lane >> 4;
  int qt = blockIdx.x, h = blockIdx.y;
  int bz = blockIdx.z;
  int b = bz & (cB - 1), split = bz >> 1;
  int q0a = qt * 128 + wave * 16;
  int q0b = q0a + 64;
  int kbase = split * SPLT_T * ACK;
  int NIT = (split == KSPLIT - 1) ? (cL / ACK - (KSPLIT - 1) * SPLT_T) : SPLT_T;

  const u16* qpa = Q + ((size_t)(b * cNH + h) * cS + q0a) * cHD;
  const u16* qpb = qpa + (size_t)64 * cHD;
  const char* kp = (const char*)(K + ((size_t)(b * cNH + h) * cL + kbase) * cHD);
  const u16* vp = Vt + (size_t)(b * cNH + h) * cHD * cL + kbase;
  u16* pwA = &pbuf[wave][0][0];
  u16* pwB = &pbuf[wave][1][0];

  int P0 = wave * 1024 + lane * 16;
  int P1 = P0 + 4096;
  int s0 = P0 ^ (((P0 >> 7) & 7) << 4);
  int s1 = P1 ^ (((P1 >> 7) & 7) << 4);
  int fsw0 = (quad * 16) ^ ((l15 & 7) << 4);
  int fsw1 = (64 + quad * 16) ^ ((l15 & 7) << 4);

  s16x8 qa0 = ld_frag(qpa + (size_t)l15 * cHD + quad * 8);
  s16x8 qa1 = ld_frag(qpa + (size_t)l15 * cHD + 32 + quad * 8);
  s16x8 qb0f = ld_frag(qpb + (size_t)l15 * cHD + quad * 8);
  s16x8 qb1f = ld_frag(qpb + (size_t)l15 * cHD + 32 + quad * 8);

  gl_lds16((const u16*)(kp + s0), (u16*)((char*)&kls[0][0] + wave * 1024));
  gl_lds16((const u16*)(kp + s1), (u16*)((char*)&kls[0][0] + 4096 + wave * 1024));

  f32x4 oacc[2][4] = {};
  float mrowA[4], lrowA[4], mrowB[4], lrowB[4];
  #pragma unroll
  for (int i = 0; i < 4; i++) {
    mrowA[i] = -1e30f; lrowA[i] = 0.f;
    mrowB[i] = -1e30f; lrowB[i] = 0.f;
  }

  constexpr float SCL = 0.125f * 1.4426950408889634f;

  for (int kt = 0; kt < NIT; kt++) {
    int cur = kt & 1;
    uint4 v01[4];
    #pragma unroll
    for (int dt = 0; dt < 2; dt++) {
      const u16* vr = vp + (size_t)(dt * 16 + l15) * cL + kt * ACK;
      v01[2 * dt]     = *(const uint4*)(vr + quad * 8);
      v01[2 * dt + 1] = *(const uint4*)(vr + 32 + quad * 8);
    }
    asm volatile("" ::: "memory");
    __builtin_amdgcn_s_barrier();
    asm volatile("" ::: "memory");
    int nk = kt + 1; if (nk == NIT) nk = 0;
    const char* kn = kp + (size_t)nk * (ACK * cHD * 2);
    gl_lds16((const u16*)(kn + s0), (u16*)((char*)&kls[cur ^ 1][0] + wave * 1024));
    gl_lds16((const u16*)(kn + s1), (u16*)((char*)&kls[cur ^ 1][0] + 4096 + wave * 1024));
    asm volatile("s_waitcnt vmcnt(6)" ::: "memory");
    __builtin_amdgcn_s_barrier();
    asm volatile("" ::: "memory");
    const char* kc = (const char*)&kls[cur][0];
    f32x4 scA[4], scB[4];
    __builtin_amdgcn_s_setprio(1);
    #pragma unroll
    for (int nt = 0; nt < 4; nt++) {
      s16x8 kf0 = *(const s16x8*)(kc + (nt * 16 + l15) * 128 + fsw0);
      s16x8 kf1 = *(const s16x8*)(kc + (nt * 16 + l15) * 128 + fsw1);
      f32x4 a = {};
      a = __builtin_amdgcn_mfma_f32_16x16x32_bf16(qa0, kf0, a, 0, 0, 0);
      a = __builtin_amdgcn_mfma_f32_16x16x32_bf16(qa1, kf1, a, 0, 0, 0);
      scA[nt] = a * SCL;
      f32x4 c = {};
      c = __builtin_amdgcn_mfma_f32_16x16x32_bf16(qb0f, kf0, c, 0, 0, 0);
      c = __builtin_amdgcn_mfma_f32_16x16x32_bf16(qb1f, kf1, c, 0, 0, 0);
      scB[nt] = c * SCL;
    }
    __builtin_amdgcn_s_setprio(0);
    float mxA[4], mxB[4];
    #pragma unroll
    for (int i = 0; i < 4; i++) {
      mxA[i] = fmaxf(fmaxf(scA[0][i], scA[1][i]), fmaxf(scA[2][i], scA[3][i]));
      mxB[i] = fmaxf(fmaxf(scB[0][i], scB[1][i]), fmaxf(scB[2][i], scB[3][i]));
    }
    #pragma unroll
    for (int i = 0; i < 4; i++) {
      mxA[i] = dpp_fmax<0xB1>(mxA[i]);  mxB[i] = dpp_fmax<0xB1>(mxB[i]);
      mxA[i] = dpp_fmax<0x4E>(mxA[i]);  mxB[i] = dpp_fmax<0x4E>(mxB[i]);
      mxA[i] = dpp_fmax<0x141>(mxA[i]); mxB[i] = dpp_fmax<0x141>(mxB[i]);
      mxA[i] = dpp_fmax<0x140>(mxA[i]); mxB[i] = dpp_fmax<0x140>(mxB[i]);
    }
    bool needA = (mxA[0] > mrowA[0]) | (mxA[1] > mrowA[1]) |
                 (mxA[2] > mrowA[2]) | (mxA[3] > mrowA[3]);
    if (__any(needA)) {
      float alpha[4];
      #pragma unroll
      for (int i = 0; i < 4; i++) {
        float mn = fmaxf(mrowA[i], mxA[i]);
        alpha[i] = exp2f(mrowA[i] - mn);
        mrowA[i] = mn;
        lrowA[i] *= alpha[i];
      }
      #pragma unroll
      for (int dt = 0; dt < 4; dt++)
        #pragma unroll
        for (int i = 0; i < 4; i++) oacc[0][dt][i] *= alpha[i];
    }
    bool needB = (mxB[0] > mrowB[0]) | (mxB[1] > mrowB[1]) |
                 (mxB[2] > mrowB[2]) | (mxB[3] > mrowB[3]);
    if (__any(needB)) {
      float alpha[4];
      #pragma unroll
      for (int i = 0; i < 4; i++) {
        float mn = fmaxf(mrowB[i], mxB[i]);
        alpha[i] = exp2f(mrowB[i] - mn);
        mrowB[i] = mn;
        lrowB[i] *= alpha[i];
      }
      #pragma unroll
      for (int dt = 0; dt < 4; dt++)
        #pragma unroll
        for (int i = 0; i < 4; i++) oacc[1][dt][i] *= alpha[i];
    }
    {
      float ps[4] = {};
      #pragma unroll
      for (int nt = 0; nt < 4; nt++)
        #pragma unroll
        for (int i = 0; i < 4; i++) {
          float p = exp2f(scA[nt][i] - mrowA[i]);
          ps[i] += p;
          pwA[(quad * 4 + i) * PLD + nt * 16 + l15] = f2u_rt(p);
        }
      #pragma unroll
      for (int i = 0; i < 4; i++) lrowA[i] += ps[i];
    }
    uint4 v23[4];
    #pragma unroll
    for (int dt = 2; dt < 4; dt++) {
      const u16* vr = vp + (size_t)(dt * 16 + l15) * cL + kt * ACK;
      v23[2 * (dt - 2)]     = *(const uint4*)(vr + quad * 8);
      v23[2 * (dt - 2) + 1] = *(const uint4*)(vr + 32 + quad * 8);
    }
    {
      float ps[4] = {};
      #pragma unroll
      for (int nt = 0; nt < 4; nt++)
        #pragma unroll
        for (int i = 0; i < 4; i++) {
          float p = exp2f(scB[nt][i] - mrowB[i]);
          ps[i] += p;
          pwB[(quad * 4 + i) * PLD + nt * 16 + l15] = f2u_rt(p);
        }
      #pragma unroll
      for (int i = 0; i < 4; i++) lrowB[i] += ps[i];
    }
    s16x8 pfA0 = *(const s16x8*)&pwA[l15 * PLD + quad * 8];
    s16x8 pfA1 = *(const s16x8*)&pwA[l15 * PLD + 32 + quad * 8];
    s16x8 pfB0 = *(const s16x8*)&pwB[l15 * PLD + quad * 8];
    s16x8 pfB1 = *(const s16x8*)&pwB[l15 * PLD + 32 + quad * 8];
    __builtin_amdgcn_s_setprio(1);
    #pragma unroll
    for (int dt = 0; dt < 2; dt++) {
      oacc[0][dt] = __builtin_amdgcn_mfma_f32_16x16x32_bf16(pfA0, u4_frag(v01[2 * dt]), oacc[0][dt], 0, 0, 0);
      oacc[0][dt] = __builtin_amdgcn_mfma_f32_16x16x32_bf16(pfA1, u4_frag(v01[2 * dt + 1]), oacc[0][dt], 0, 0, 0);
      oacc[1][dt] = __builtin_amdgcn_mfma_f32_16x16x32_bf16(pfB0, u4_frag(v01[2 * dt]), oacc[1][dt], 0, 0, 0);
      oacc[1][dt] = __builtin_amdgcn_mfma_f32_16x16x32_bf16(pfB1, u4_frag(v01[2 * dt + 1]), oacc[1][dt], 0, 0, 0);
    }
    #pragma unroll
    for (int dt = 2; dt < 4; dt++) {
      int vi = 2 * (dt - 2);
      oacc[0][dt] = __builtin_amdgcn_mfma_f32_16x16x32_bf16(pfA0, u4_frag(v23[vi]), oacc[0][dt], 0, 0, 0);
      oacc[0][dt] = __builtin_amdgcn_mfma_f32_16x16x32_bf16(pfA1, u4_frag(v23[vi + 1]), oacc[0][dt], 0, 0, 0);
      oacc[1][dt] = __builtin_amdgcn_mfma_f32_16x16x32_bf16(pfB0, u4_frag(v23[vi]), oacc[1][dt], 0, 0, 0);
      oacc[1][dt] = __builtin_amdgcn_mfma_f32_16x16x32_bf16(pfB1, u4_frag(v23[vi + 1]), oacc[1][dt], 0, 0, 0);
    }
    __builtin_amdgcn_s_setprio(0);
  }
  #pragma unroll
  for (int off = 1; off < 16; off <<= 1)
    #pragma unroll
    for (int i = 0; i < 4; i++) {
      lrowA[i] += __shfl_xor(lrowA[i], off);
      lrowB[i] += __shfl_xor(lrowB[i], off);
    }
  float* ob = (split == 0) ? o0 : (split == 1) ? o1 : o2;
  #pragma unroll
  for (int x = 0; x < 2; x++) {
    int qbase = x ? q0b : q0a;
    #pragma unroll
    for (int i = 0; i < 4; i++) {
      int q = qbase + quad * 4 + i;
      size_t Rl = (size_t)(b * cNH + h) * cS + q;
      float* orow = ob + Rl * cHD;
      #pragma unroll
      for (int dt = 0; dt < 4; dt++)
        orow[dt * 16 + l15] = oacc[x][dt][i];
      if (l15 == 0) {
        mlbuf[((size_t)split * NRB + Rl) * 2]     = x ? mrowB[i] : mrowA[i];
        mlbuf[((size_t)split * NRB + Rl) * 2 + 1] = x ? lrowB[i] : lrowA[i];
      }
    }
  }
}

// ---------------- split-K merge: combine three softmax partials -> bf16 ctx ----------------
__global__ __launch_bounds__(256) void attn_merge(
    const float* __restrict__ o0, const float* __restrict__ o1,
    const float* __restrict__ o2,
    const float* __restrict__ mlbuf, u16* __restrict__ ctx)
{
  int t = threadIdx.x;
  int R = blockIdx.x * 4 + (t >> 6);   // (b*cNH+h)*cS + q
  int d = t & 63;
  float ms[KSPLIT], ls[KSPLIT];
  float m = -1e30f;
  #pragma unroll
  for (int s = 0; s < KSPLIT; s++) {
    ms[s] = mlbuf[((size_t)s * NRB + R) * 2];
    ls[s] = mlbuf[((size_t)s * NRB + R) * 2 + 1];
    m = fmaxf(m, ms[s]);
  }
  const float* ops[KSPLIT] = {o0, o1, o2};
  float num = 0.f, den = 0.f;
  #pragma unroll
  for (int s = 0; s < KSPLIT; s++) {
    float a = exp2f(ms[s] - m);
    num += ops[s][(size_t)R * cHD + d] * a;
    den += ls[s] * a;
  }
  float val = num / den;
  int q = R & (cS - 1), h = (R >> 10) & 15, b = R >> 14;
  ctx[((size_t)b * cS + q) * cH + h * cHD + d] = f2u(val);
}

extern "C" void kernel_launch(void* const* d_in, const int* in_sizes, int n_in,
                              void* d_out, int out_size, void* d_ws, size_t ws_size,
                              hipStream_t stream)
{
  const float* hidden = (const float*)d_in[0];
  const float* cache  = (const float*)d_in[1];
  const float* ln_s   = (const float*)d_in[2];
  const float* ln_b   = (const float*)d_in[3];
  const float* Wq     = (const float*)d_in[4];
  const float* Wk     = (const float*)d_in[5];
  const float* Wv     = (const float*)d_in[6];
  const float* Wo     = (const float*)d_in[7];
  const float* gate   = (const float*)d_in[8];
  const float* lsc    = (const float*)d_in[9];
  float* outp = (float*)d_out;

  // ws: kvin 20.97M | vt 20.97M | opart(splits 0,1) 16.78M  (~58.7 MB)
  u16* kvin = (u16*)d_ws;
  u16* vt   = kvin + (size_t)cB * cL * cH;
  float* opart = (float*)(vt + (size_t)cB * cL * cH);
  float* o0 = opart;
  float* o1 = opart + (size_t)cB * cNH * cS * cHD;          // +8.39MB
  // aliases into kvin (dead rows by the time these are written):
  u16* qb  = kvin;                                // [0, 4.19M) written by Q GEMM (last kvin reader)
  u16* ctx = kvin + (size_t)2 * 1024 * 1024;      // [4.19M, 8.39M) written by attn_merge
  float* o2 = (float*)(kvin + (size_t)4 * 1024 * 1024);   // bytes [8.39M, 16.78M)
  float* mlbuf = (float*)(kvin + (size_t)8 * 1024 * 1024);// bytes [16.78M, 17.57M), 3 splits
  // scratch parked in d_out (overwritten by memcpy/final-LN at the end):
  u16* kb = (u16*)(outp + (size_t)cB * cS * cH);
  u16* Wt = (u16*)(outp + (size_t)(1 + 3) * cB * cS * cH);
  u16* Wt_q = Wt;
  u16* Wt_k = Wt + (size_t)cH * cH;
  u16* Wt_o = Wt + (size_t)3 * cH * cH;

  // 1) prep: weight transpose + cache->kvin + pre-norm, one launch
  prep<<<14336, 256, 0, stream>>>(Wq, Wk, Wv, Wo, Wt, cache, kvin,
                                  hidden, ln_s, ln_b);

  // 2) fused K|V projection (RoPE fused into K epilogue), then Q (RoPE fused)
  mgemm<<<dim3(16, (cB * cL) / GBM), 256, 0, stream>>>(
      kvin, Wt_k, cL, 0, cL, cL, 5, kb, vt, nullptr, nullptr, nullptr, nullptr, nullptr);
  mgemm<<<dim3(8, (cB * cS) / GBM), 256, 0, stream>>>(
      kvin, Wt_q, cS, cW * cS, cL, cS, 1, qb, nullptr, nullptr, nullptr, nullptr, nullptr, nullptr);

  // 3) 3-way split-K MFMA flash attention (2 q-tiles/wave) -> partials -> merge
  attn_mfma<<<dim3(cS / 128, cNH, cB * KSPLIT), 256, 0, stream>>>(
      qb, kb, vt, o0, o1, o2, mlbuf);
  attn_merge<<<(cB * cNH * cS) / 4, 256, 0, stream>>>(o0, o1, o2, mlbuf, ctx);

  // 4) ctx @ Wo with fused gated residual -> output f32
  mgemm<<<dim3(8, (cB * cS) / GBM), 256, 0, stream>>>(
      ctx, Wt_o, cB * cS, 0, cB * cS, cB * cS, 2, nullptr, nullptr,
      hidden, cache, gate, lsc, outp);

  // 5) new_cache[0:3] = cache[1:4]
  hipMemcpyAsync(outp + (size_t)cB * cS * cH, cache + (size_t)cB * cS * cH,
                 (size_t)(cW - 1) * cB * cS * cH * sizeof(float),
                 hipMemcpyDeviceToDevice, stream);
  // 6) final layernorm -> new_cache slot 3
  ln_f32<<<cB * cS, 256, 0, stream>>>(outp, outp + (size_t)cW * cB * cS * cH, ln_s, ln_b);
}

// Round 11
// 352.641 us; speedup vs baseline: 1.2444x; 1.0374x over previous
//
#include <hip/hip_runtime.h>
#include <math.h>

typedef unsigned short u16;

constexpr int cB = 2;
constexpr int cS = 1024;
constexpr int cH = 1024;
constexpr int cNH = 16;
constexpr int cHD = 64;
constexpr int cW = 4;
constexpr int cL = (cW + 1) * cS; // 5120
constexpr float cEPS = 1e-5f;

typedef short s16x8 __attribute__((ext_vector_type(8)));   // 8 bf16 (4 VGPRs)
typedef float f32x4 __attribute__((ext_vector_type(4)));   // MFMA C/D

__device__ __forceinline__ float u2f(u16 u) {
  union { unsigned int i; float f; } x; x.i = ((unsigned int)u) << 16; return x.f;
}
__device__ __forceinline__ u16 f2u(float f) {
  union { float f; unsigned int i; } x; x.f = f;
  unsigned int i = x.i;
  i += 0x7fffu + ((i >> 16) & 1u); // RNE
  return (u16)(i >> 16);
}
// fast path: native v_cvt bf16 (RNE), 1 VALU op
__device__ __forceinline__ u16 f2u_rt(float f) {
  union { __bf16 b; u16 u; } c; c.b = (__bf16)f; return c.u;
}
__device__ __forceinline__ s16x8 ld_frag(const u16* p) {
  uint4 v = *(const uint4*)p;
  union { uint4 u; s16x8 s; } c; c.u = v; return c.s;
}
__device__ __forceinline__ s16x8 u4_frag(uint4 v) {
  union { uint4 u; s16x8 s; } c; c.u = v; return c.s;
}
// async 16B global -> LDS (dest = wave-uniform base + lane*16)
__device__ __forceinline__ void gl_lds16(const u16* g, u16* l) {
  __builtin_amdgcn_global_load_lds(
      (const __attribute__((address_space(1))) unsigned int*)g,
      (__attribute__((address_space(3))) unsigned int*)l, 16, 0, 0);
}
// VALU-pipe cross-lane fmax via DPP (ctrl must be a literal -> template param)
template <int CTRL>
__device__ __forceinline__ float dpp_fmax(float x) {
  union { float f; int i; } a, r;
  a.f = x;
  r.i = __builtin_amdgcn_update_dpp(a.i, a.i, CTRL, 0xF, 0xF, true);
  return fmaxf(x, r.f);
}

// ---------------- LayerNorm f32 -> f32 (final LN) ----------------
__global__ __launch_bounds__(256) void ln_f32(
    const float* __restrict__ src, float* __restrict__ dst,
    const float* __restrict__ scale, const float* __restrict__ bias)
{
  int r = blockIdx.x;
  int t = threadIdx.x;
  const float* sp = src + (size_t)r * cH;
  float4 x = ((const float4*)sp)[t];
  float s1 = x.x + x.y + x.z + x.w;
  float s2 = x.x * x.x + x.y * x.y + x.z * x.z + x.w * x.w;
  #pragma unroll
  for (int off = 32; off > 0; off >>= 1) {
    s1 += __shfl_down(s1, off);
    s2 += __shfl_down(s2, off);
  }
  __shared__ float w1[4], w2[4];
  __shared__ float stat[2];
  int wid = t >> 6, lid = t & 63;
  if (lid == 0) { w1[wid] = s1; w2[wid] = s2; }
  __syncthreads();
  if (t == 0) {
    float a = w1[0] + w1[1] + w1[2] + w1[3];
    float b = w2[0] + w2[1] + w2[2] + w2[3];
    float mu = a * (1.f / cH);
    float var = b * (1.f / cH) - mu * mu;
    if (var < 0.f) var = 0.f;
    stat[0] = mu; stat[1] = rsqrtf(var + cEPS);
  }
  __syncthreads();
  float mu = stat[0], rs = stat[1];
  int h0 = t * 4;
  float4 sc = *(const float4*)(scale + h0);
  float4 bi = *(const float4*)(bias + h0);
  float4 o;
  o.x = (x.x - mu) * rs * sc.x + bi.x;
  o.y = (x.y - mu) * rs * sc.y + bi.y;
  o.z = (x.z - mu) * rs * sc.z + bi.z;
  o.w = (x.w - mu) * rs * sc.w + bi.w;
  *(float4*)(dst + (size_t)r * cH + h0) = o;
}

// ---- prep: wtrans(4) + cache2kv + ln_bf16 + RoPE table, one launch ----
// bid [0,4096): weight transpose; [4096,12288): cache->kvin;
// [12288,14336): pre-norm -> kvin tail; [14336,14464): cos/sin table.
__global__ __launch_bounds__(256) void prep(
    const float* __restrict__ W0, const float* __restrict__ W1,
    const float* __restrict__ W2, const float* __restrict__ W3,
    u16* __restrict__ Wt,
    const float* __restrict__ cache, u16* __restrict__ kvin,
    const float* __restrict__ hidden,
    const float* __restrict__ scale, const float* __restrict__ bias,
    float2* __restrict__ ropetab)
{
  __shared__ float tile[32][33];
  __shared__ float red[10];
  int t = threadIdx.x;
  int bid = blockIdx.x;
  if (bid < 4096) {
    int mat = bid >> 10;
    int k0 = ((bid >> 5) & 31) * 32, n0 = (bid & 31) * 32;
    const float* W = (mat == 0) ? W0 : (mat == 1) ? W1 : (mat == 2) ? W2 : W3;
    u16* out = Wt + (size_t)mat * cH * cH;
    int r = t >> 3, c = (t & 7) * 4;
    float4 v = *(const float4*)(W + (size_t)(k0 + r) * cH + n0 + c);
    tile[r][c] = v.x; tile[r][c + 1] = v.y; tile[r][c + 2] = v.z; tile[r][c + 3] = v.w;
    __syncthreads();
    ushort4 o; u16* op = (u16*)&o;
    #pragma unroll
    for (int j = 0; j < 4; j++) op[j] = f2u(tile[c + j][r]);
    *(ushort4*)(out + (size_t)(n0 + r) * cH + k0 + c) = o;
  } else if (bid < 12288) {
    int blk = bid - 4096;          // cB*cW*cS = 8192
    int b = blk >> 12, w = (blk >> 10) & 3, s = blk & 1023;
    const float* src = cache + ((size_t)((w * cB + b) * cS + s)) * cH;
    u16* dst = kvin + ((size_t)(b * cL + w * cS + s)) * cH;
    float4 v = *(const float4*)(src + t * 4);
    ushort4 o; u16* op = (u16*)&o;
    op[0] = f2u(v.x); op[1] = f2u(v.y); op[2] = f2u(v.z); op[3] = f2u(v.w);
    *(ushort4*)(dst + t * 4) = o;
  } else if (bid < 14336) {
    int r = bid - 12288;           // 0..cB*cS-1
    const float* sp = hidden + (size_t)r * cH;
    float4 x = ((const float4*)sp)[t];
    float s1 = x.x + x.y + x.z + x.w;
    float s2 = x.x * x.x + x.y * x.y + x.z * x.z + x.w * x.w;
    #pragma unroll
    for (int off = 32; off > 0; off >>= 1) {
      s1 += __shfl_down(s1, off);
      s2 += __shfl_down(s2, off);
    }
    int wid = t >> 6, lid = t & 63;
    if (lid == 0) { red[wid] = s1; red[4 + wid] = s2; }
    __syncthreads();
    if (t == 0) {
      float a = red[0] + red[1] + red[2] + red[3];
      float b2 = red[4] + red[5] + red[6] + red[7];
      float mu = a * (1.f / cH);
      float var = b2 * (1.f / cH) - mu * mu;
      if (var < 0.f) var = 0.f;
      red[8] = mu; red[9] = rsqrtf(var + cEPS);
    }
    __syncthreads();
    float mu = red[8], rs = red[9];
    int h0 = t * 4;
    float4 sc = *(const float4*)(scale + h0);
    float4 bi = *(const float4*)(bias + h0);
    int b = r >> 10, s = r & (cS - 1);
    u16* dp = kvin + ((size_t)(b * cL + cW * cS + s)) * cH + h0;
    ushort4 o; u16* op = (u16*)&o;
    op[0] = f2u((x.x - mu) * rs * sc.x + bi.x);
    op[1] = f2u((x.y - mu) * rs * sc.y + bi.y);
    op[2] = f2u((x.z - mu) * rs * sc.z + bi.z);
    op[3] = f2u((x.w - mu) * rs * sc.w + bi.w);
    *(ushort4*)dp = o;
  } else {
    // RoPE table: [pos][d] (1024 x 32) float2(cos, sin) — math bitwise
    // identical to the old in-epilogue sincosf path.
    int idx = (bid - 14336) * 256 + t;   // = pos*32 + d
    int pos = idx >> 5, d = idx & 31;
    constexpr float RC = 13.287712379549449f / 32.f;   // log2(10000)/32
    float fr = exp2f(-(float)d * RC);
    float sn, cs;
    sincosf((float)pos * fr, &sn, &cs);
    ropetab[idx] = make_float2(cs, sn);
  }
}

// ---------------- MFMA GEMM (m97 staging; RoPE-table fused mode-1 epilogue) ----------------
// mode 5: fused K|V projection (n0<1024 -> K/mode1, else V/mode3).
// mode 6: flattened KV+Q combo launch (1408 blocks): bid<1280 -> KV (as mode
// 5, Wt+cH*cH base), else Q (mode 1, Wt base, out Cb3).  Q blocks pack into
// the KV grid's drain — one launch, no gap.
constexpr int GBM = 128, GBN = 128, TLD = 136;

__global__ __launch_bounds__(256) void mgemm(
    const u16* __restrict__ A, const u16* __restrict__ Wt,
    int a_rpb, int a_base, int a_stride,
    int c_rpb, int mode,
    u16* __restrict__ Cb, u16* __restrict__ Cb2, u16* __restrict__ Cb3,
    const float2* __restrict__ ropetab,
    const float* __restrict__ hidden, const float* __restrict__ cachefull,
    const float* __restrict__ gate, const float* __restrict__ lsc,
    float* __restrict__ outp)
{
  __shared__ __align__(16) u16 smem[128 * TLD];

  int t = threadIdx.x;
  int bx = blockIdx.x, by = blockIdx.y;
  int eff_mode = mode;
  const u16* WtU = Wt;
  u16* CbU = Cb; u16* Cb2U = Cb2;
  if (mode == 6) {
    if (bx < 1280) {               // KV part: grid 16 x 80
      eff_mode = 5;
      by = bx >> 4; bx = bx & 15;
      a_rpb = cL; a_base = 0; a_stride = cL; c_rpb = cL;
      WtU = Wt + (size_t)cH * cH;  // Wt_k (V rows follow contiguously)
    } else {                       // Q part: grid 8 x 16
      eff_mode = 1;
      int id = bx - 1280;
      by = id >> 3; bx = id & 7;
      a_rpb = cS; a_base = cW * cS; a_stride = cL; c_rpb = cS;
      WtU = Wt;                    // Wt_q
      CbU = Cb3;
    }
  }

  int m0 = by * GBM, n0 = bx * GBN;
  int wave = t >> 6, lane = t & 63, l15 = lane & 15, quad = lane >> 4;
  int wm = (wave >> 1) * 64, wn = (wave & 1) * 64;

  int sr = t >> 2, sk = (t & 3) * 8;
  int rg0 = m0 + sr, rg1 = rg0 + 64;
  int ab0 = rg0 / a_rpb, ab1 = rg1 / a_rpb;
  const u16* arow0 = A + (size_t)(ab0 * a_stride + a_base + (rg0 - ab0 * a_rpb)) * cH + sk;
  const u16* arow1 = A + (size_t)(ab1 * a_stride + a_base + (rg1 - ab1 * a_rpb)) * cH + sk;
  const u16* wrow0 = WtU + (size_t)(n0 + sr) * cH + sk;
  const u16* wrow1 = WtU + (size_t)(n0 + sr + 64) * cH + sk;

  u16* As0 = smem;
  u16* Bs0 = smem + 8192;
  int wofs = wave * 512;

  f32x4 acc[4][4] = {};

  gl_lds16(arow0, As0 + wofs);
  gl_lds16(arow1, As0 + 2048 + wofs);
  gl_lds16(wrow0, Bs0 + wofs);
  gl_lds16(wrow1, Bs0 + 2048 + wofs);

  constexpr int NK = cH / 32;
  for (int kt = 0; kt < NK; kt++) {
    int cur = kt & 1;
    asm volatile("" ::: "memory");
    __builtin_amdgcn_s_barrier();
    asm volatile("" ::: "memory");
    int nk = kt + 1; if (nk == NK) nk = 0;
    int nko = nk * 32;
    u16* Abn = As0 + (cur ^ 1) * 4096;
    u16* Bbn = Bs0 + (cur ^ 1) * 4096;
    gl_lds16(arow0 + nko, Abn + wofs);
    gl_lds16(arow1 + nko, Abn + 2048 + wofs);
    gl_lds16(wrow0 + nko, Bbn + wofs);
    gl_lds16(wrow1 + nko, Bbn + 2048 + wofs);
    asm volatile("s_waitcnt vmcnt(4)" ::: "memory");
    __builtin_amdgcn_s_barrier();
    asm volatile("" ::: "memory");
    const u16* Ab = As0 + cur * 4096;
    const u16* Bb = Bs0 + cur * 4096;
    s16x8 af[4], bf[4];
    #pragma unroll
    for (int mt = 0; mt < 4; mt++)
      af[mt] = *(const s16x8*)&Ab[(wm + mt * 16 + l15) * 32 + quad * 8];
    #pragma unroll
    for (int nt = 0; nt < 4; nt++)
      bf[nt] = *(const s16x8*)&Bb[(wn + nt * 16 + l15) * 32 + quad * 8];
    #pragma unroll
    for (int mt = 0; mt < 4; mt++)
      #pragma unroll
      for (int nt = 0; nt < 4; nt++)
        acc[mt][nt] = __builtin_amdgcn_mfma_f32_16x16x32_bf16(af[mt], bf[nt], acc[mt][nt], 0, 0, 0);
  }

  int mode_eff = eff_mode;
  u16* Cout = CbU;
  int nbase = n0;
  if (eff_mode == 5) {
    if (n0 < cH) { mode_eff = 1; }
    else { mode_eff = 3; Cout = Cb2U; nbase = n0 - cH; }
  }

  if (mode_eff == 1) {
    // fused RoPE via table: dh0 = l15 (nt0/nt2 pair), dh1 = 16+l15 (nt1/nt3)
    #pragma unroll
    for (int mt = 0; mt < 4; mt++)
      #pragma unroll
      for (int i = 0; i < 4; i++) {
        int rg = m0 + wm + mt * 16 + quad * 4 + i;
        int bo = rg / c_rpb, lo = rg - bo * c_rpb;
        int pos = lo & (cS - 1);
        const float2* tb = ropetab + (size_t)pos * 32;
        float2 c0 = tb[l15];
        float2 c1 = tb[l15 + 16];
        float v0 = acc[mt][0][i], v1 = acc[mt][1][i];
        float v2 = acc[mt][2][i], v3 = acc[mt][3][i];
        float rr[4];
        rr[0] = v0 * c0.x - v2 * c0.y;
        rr[1] = v1 * c1.x - v3 * c1.y;
        rr[2] = v0 * c0.y + v2 * c0.x;
        rr[3] = v1 * c1.y + v3 * c1.x;
        #pragma unroll
        for (int nt = 0; nt < 4; nt++) {
          int n = nbase + wn + nt * 16 + l15;
          int h = n >> 6, d = n & 63;
          Cout[(((size_t)(bo * cNH + h) * c_rpb + lo) * cHD) + d] = f2u(rr[nt]);
        }
      }
  } else if (mode_eff == 3) {
    u16* t2 = smem;
    asm volatile("s_waitcnt vmcnt(0)" ::: "memory");
    __syncthreads();
    #pragma unroll
    for (int mt = 0; mt < 4; mt++)
      #pragma unroll
      for (int nt = 0; nt < 4; nt++) {
        ushort4 o; u16* op = (u16*)&o;
        #pragma unroll
        for (int i = 0; i < 4; i++) op[i] = f2u(acc[mt][nt][i]);
        *(ushort4*)&t2[(size_t)(wn + nt * 16 + l15) * TLD + wm + mt * 16 + quad * 4] = o;
      }
    __syncthreads();
    int n_l = t >> 1, mh = (t & 1) * 64;
    int bo = m0 / c_rpb;
    int lo = m0 - bo * c_rpb + mh;
    int n = nbase + n_l, h = n >> 6, d = n & 63;
    u16* dst = Cout + ((size_t)(bo * cNH + h) * cHD + d) * (size_t)c_rpb + lo;
    #pragma unroll
    for (int j = 0; j < 8; j++)
      *(uint4*)(dst + j * 8) = *(const uint4*)&t2[(size_t)n_l * TLD + mh + j * 8];
  } else {
    float gv[4], lv[4];
    #pragma unroll
    for (int nt = 0; nt < 4; nt++) {
      int n = n0 + wn + nt * 16 + l15;
      gv[nt] = 1.f / (1.f + __expf(-gate[n]));
      lv[nt] = lsc[n];
    }
    #pragma unroll
    for (int mt = 0; mt < 4; mt++)
      #pragma unroll
      for (int i = 0; i < 4; i++) {
        int rg = m0 + wm + mt * 16 + quad * 4 + i;
        size_t rbase = (size_t)rg * cH;
        #pragma unroll
        for (int nt = 0; nt < 4; nt++) {
          int n = n0 + wn + nt * 16 + l15;
          float hid = hidden[rbase + n];
          float cr = cachefull[(size_t)3 * cB * cS * cH + rbase + n];
          outp[rbase + n] = hid + lv[nt] * (gv[nt] * acc[mt][nt][i] + (1.f - gv[nt]) * cr);
        }
      }
  }
}

// ---------------- MFMA flash attention, 3-way split-K (r10 structure) ----------------
constexpr int ACK = 64;
constexpr int PLD = 72;
constexpr int KSPLIT = 3;
constexpr int SPLT_T = 27;           // tiles in splits 0,1 (split 2: 26)
constexpr int NRB = cB * cNH * cS;   // rows per split (32768)

__global__ __launch_bounds__(256, 3) void attn_mfma(
    const u16* __restrict__ Q, const u16* __restrict__ K, const u16* __restrict__ Vt,
    float* __restrict__ o0, float* __restrict__ o1, float* __restrict__ o2,
    float* __restrict__ mlbuf)
{
  __shared__ __align__(16) u16 kls[2][ACK * cHD];     // 16 KB
  __shared__ u16 pbuf[4][2][16 * PLD];                // 18.4 KB

  int t = threadIdx.x;
  int wave = t >> 6, lane = t & 63;
  int l15 = lane & 15, quad = lane >> 4;
  int qt = blockIdx.x, h = blockIdx.y;
  int bz = blockIdx.z;
  int b = bz & (cB - 1), split = bz >> 1;
  int q0a = qt * 128 + wave * 16;
  int q0b = q0a + 64;
  int kbase = split * SPLT_T * ACK;
  int NIT = (split == KSPLIT - 1) ? (cL / ACK - (KSPLIT - 1) * SPLT_T) : SPLT_T;

  const u16* qpa = Q + ((size_t)(b * cNH + h) * cS + q0a) * cHD;
  const u16* qpb = qpa + (size_t)64 * cHD;
  const char* kp = (const char*)(K + ((size_t)(b * cNH + h) * cL + kbase) * cHD);
  const u16* vp = Vt + (size_t)(b * cNH + h) * cHD * cL + kbase;
  u16* pwA = &pbuf[wave][0][0];
  u16* pwB = &pbuf[wave][1][0];

  int P0 = wave * 1024 + lane * 16;
  int P1 = P0 + 4096;
  int s0 = P0 ^ (((P0 >> 7) & 7) << 4);
  int s1 = P1 ^ (((P1 >> 7) & 7) << 4);
  int fsw0 = (quad * 16) ^ ((l15 & 7) << 4);
  int fsw1 = (64 + quad * 16) ^ ((l15 & 7) << 4);

  s16x8 qa0 = ld_frag(qpa + (size_t)l15 * cHD + quad * 8);
  s16x8 qa1 = ld_frag(qpa + (size_t)l15 * cHD + 32 + quad * 8);
  s16x8 qb0f = ld_frag(qpb + (size_t)l15 * cHD + quad * 8);
  s16x8 qb1f = ld_frag(qpb + (size_t)l15 * cHD + 32 + quad * 8);

  gl_lds16((const u16*)(kp + s0), (u16*)((char*)&kls[0][0] + wave * 1024));
  gl_lds16((const u16*)(kp + s1), (u16*)((char*)&kls[0][0] + 4096 + wave * 1024));

  f32x4 oacc[2][4] = {};
  float mrowA[4], lrowA[4], mrowB[4], lrowB[4];
  #pragma unroll
  for (int i = 0; i < 4; i++) {
    mrowA[i] = -1e30f; lrowA[i] = 0.f;
    mrowB[i] = -1e30f; lrowB[i] = 0.f;
  }

  constexpr float SCL = 0.125f * 1.4426950408889634f;

  for (int kt = 0; kt < NIT; kt++) {
    int cur = kt & 1;
    uint4 v01[4];
    #pragma unroll
    for (int dt = 0; dt < 2; dt++) {
      const u16* vr = vp + (size_t)(dt * 16 + l15) * cL + kt * ACK;
      v01[2 * dt]     = *(const uint4*)(vr + quad * 8);
      v01[2 * dt + 1] = *(const uint4*)(vr + 32 + quad * 8);
    }
    asm volatile("" ::: "memory");
    __builtin_amdgcn_s_barrier();
    asm volatile("" ::: "memory");
    int nk = kt + 1; if (nk == NIT) nk = 0;
    const char* kn = kp + (size_t)nk * (ACK * cHD * 2);
    gl_lds16((const u16*)(kn + s0), (u16*)((char*)&kls[cur ^ 1][0] + wave * 1024));
    gl_lds16((const u16*)(kn + s1), (u16*)((char*)&kls[cur ^ 1][0] + 4096 + wave * 1024));
    asm volatile("s_waitcnt vmcnt(6)" ::: "memory");
    __builtin_amdgcn_s_barrier();
    asm volatile("" ::: "memory");
    const char* kc = (const char*)&kls[cur][0];
    f32x4 scA[4], scB[4];
    __builtin_amdgcn_s_setprio(1);
    #pragma unroll
    for (int nt = 0; nt < 4; nt++) {
      s16x8 kf0 = *(const s16x8*)(kc + (nt * 16 + l15) * 128 + fsw0);
      s16x8 kf1 = *(const s16x8*)(kc + (nt * 16 + l15) * 128 + fsw1);
      f32x4 a = {};
      a = __builtin_amdgcn_mfma_f32_16x16x32_bf16(qa0, kf0, a, 0, 0, 0);
      a = __builtin_amdgcn_mfma_f32_16x16x32_bf16(qa1, kf1, a, 0, 0, 0);
      scA[nt] = a * SCL;
      f32x4 c = {};
      c = __builtin_amdgcn_mfma_f32_16x16x32_bf16(qb0f, kf0, c, 0, 0, 0);
      c = __builtin_amdgcn_mfma_f32_16x16x32_bf16(qb1f, kf1, c, 0, 0, 0);
      scB[nt] = c * SCL;
    }
    __builtin_amdgcn_s_setprio(0);
    float mxA[4], mxB[4];
    #pragma unroll
    for (int i = 0; i < 4; i++) {
      mxA[i] = fmaxf(fmaxf(scA[0][i], scA[1][i]), fmaxf(scA[2][i], scA[3][i]));
      mxB[i] = fmaxf(fmaxf(scB[0][i], scB[1][i]), fmaxf(scB[2][i], scB[3][i]));
    }
    #pragma unroll
    for (int i = 0; i < 4; i++) {
      mxA[i] = dpp_fmax<0xB1>(mxA[i]);  mxB[i] = dpp_fmax<0xB1>(mxB[i]);
      mxA[i] = dpp_fmax<0x4E>(mxA[i]);  mxB[i] = dpp_fmax<0x4E>(mxB[i]);
      mxA[i] = dpp_fmax<0x141>(mxA[i]); mxB[i] = dpp_fmax<0x141>(mxB[i]);
      mxA[i] = dpp_fmax<0x140>(mxA[i]); mxB[i] = dpp_fmax<0x140>(mxB[i]);
    }
    bool needA = (mxA[0] > mrowA[0]) | (mxA[1] > mrowA[1]) |
                 (mxA[2] > mrowA[2]) | (mxA[3] > mrowA[3]);
    if (__any(needA)) {
      float alpha[4];
      #pragma unroll
      for (int i = 0; i < 4; i++) {
        float mn = fmaxf(mrowA[i], mxA[i]);
        alpha[i] = exp2f(mrowA[i] - mn);
        mrowA[i] = mn;
        lrowA[i] *= alpha[i];
      }
      #pragma unroll
      for (int dt = 0; dt < 4; dt++)
        #pragma unroll
        for (int i = 0; i < 4; i++) oacc[0][dt][i] *= alpha[i];
    }
    bool needB = (mxB[0] > mrowB[0]) | (mxB[1] > mrowB[1]) |
                 (mxB[2] > mrowB[2]) | (mxB[3] > mrowB[3]);
    if (__any(needB)) {
      float alpha[4];
      #pragma unroll
      for (int i = 0; i < 4; i++) {
        float mn = fmaxf(mrowB[i], mxB[i]);
        alpha[i] = exp2f(mrowB[i] - mn);
        mrowB[i] = mn;
        lrowB[i] *= alpha[i];
      }
      #pragma unroll
      for (int dt = 0; dt < 4; dt++)
        #pragma unroll
        for (int i = 0; i < 4; i++) oacc[1][dt][i] *= alpha[i];
    }
    {
      float ps[4] = {};
      #pragma unroll
      for (int nt = 0; nt < 4; nt++)
        #pragma unroll
        for (int i = 0; i < 4; i++) {
          float p = exp2f(scA[nt][i] - mrowA[i]);
          ps[i] += p;
          pwA[(quad * 4 + i) * PLD + nt * 16 + l15] = f2u_rt(p);
        }
      #pragma unroll
      for (int i = 0; i < 4; i++) lrowA[i] += ps[i];
    }
    uint4 v23[4];
    #pragma unroll
    for (int dt = 2; dt < 4; dt++) {
      const u16* vr = vp + (size_t)(dt * 16 + l15) * cL + kt * ACK;
      v23[2 * (dt - 2)]     = *(const uint4*)(vr + quad * 8);
      v23[2 * (dt - 2) + 1] = *(const uint4*)(vr + 32 + quad * 8);
    }
    {
      float ps[4] = {};
      #pragma unroll
      for (int nt = 0; nt < 4; nt++)
        #pragma unroll
        for (int i = 0; i < 4; i++) {
          float p = exp2f(scB[nt][i] - mrowB[i]);
          ps[i] += p;
          pwB[(quad * 4 + i) * PLD + nt * 16 + l15] = f2u_rt(p);
        }
      #pragma unroll
      for (int i = 0; i < 4; i++) lrowB[i] += ps[i];
    }
    s16x8 pfA0 = *(const s16x8*)&pwA[l15 * PLD + quad * 8];
    s16x8 pfA1 = *(const s16x8*)&pwA[l15 * PLD + 32 + quad * 8];
    s16x8 pfB0 = *(const s16x8*)&pwB[l15 * PLD + quad * 8];
    s16x8 pfB1 = *(const s16x8*)&pwB[l15 * PLD + 32 + quad * 8];
    __builtin_amdgcn_s_setprio(1);
    #pragma unroll
    for (int dt = 0; dt < 2; dt++) {
      oacc[0][dt] = __builtin_amdgcn_mfma_f32_16x16x32_bf16(pfA0, u4_frag(v01[2 * dt]), oacc[0][dt], 0, 0, 0);
      oacc[0][dt] = __builtin_amdgcn_mfma_f32_16x16x32_bf16(pfA1, u4_frag(v01[2 * dt + 1]), oacc[0][dt], 0, 0, 0);
      oacc[1][dt] = __builtin_amdgcn_mfma_f32_16x16x32_bf16(pfB0, u4_frag(v01[2 * dt]), oacc[1][dt], 0, 0, 0);
      oacc[1][dt] = __builtin_amdgcn_mfma_f32_16x16x32_bf16(pfB1, u4_frag(v01[2 * dt + 1]), oacc[1][dt], 0, 0, 0);
    }
    #pragma unroll
    for (int dt = 2; dt < 4; dt++) {
      int vi = 2 * (dt - 2);
      oacc[0][dt] = __builtin_amdgcn_mfma_f32_16x16x32_bf16(pfA0, u4_frag(v23[vi]), oacc[0][dt], 0, 0, 0);
      oacc[0][dt] = __builtin_amdgcn_mfma_f32_16x16x32_bf16(pfA1, u4_frag(v23[vi + 1]), oacc[0][dt], 0, 0, 0);
      oacc[1][dt] = __builtin_amdgcn_mfma_f32_16x16x32_bf16(pfB0, u4_frag(v23[vi]), oacc[1][dt], 0, 0, 0);
      oacc[1][dt] = __builtin_amdgcn_mfma_f32_16x16x32_bf16(pfB1, u4_frag(v23[vi + 1]), oacc[1][dt], 0, 0, 0);
    }
    __builtin_amdgcn_s_setprio(0);
  }
  #pragma unroll
  for (int off = 1; off < 16; off <<= 1)
    #pragma unroll
    for (int i = 0; i < 4; i++) {
      lrowA[i] += __shfl_xor(lrowA[i], off);
      lrowB[i] += __shfl_xor(lrowB[i], off);
    }
  float* ob = (split == 0) ? o0 : (split == 1) ? o1 : o2;
  #pragma unroll
  for (int x = 0; x < 2; x++) {
    int qbase = x ? q0b : q0a;
    #pragma unroll
    for (int i = 0; i < 4; i++) {
      int q = qbase + quad * 4 + i;
      size_t Rl = (size_t)(b * cNH + h) * cS + q;
      float* orow = ob + Rl * cHD;
      #pragma unroll
      for (int dt = 0; dt < 4; dt++)
        orow[dt * 16 + l15] = oacc[x][dt][i];
      if (l15 == 0) {
        mlbuf[((size_t)split * NRB + Rl) * 2]     = x ? mrowB[i] : mrowA[i];
        mlbuf[((size_t)split * NRB + Rl) * 2 + 1] = x ? lrowB[i] : lrowA[i];
      }
    }
  }
}

// ---------------- split-K merge: combine three softmax partials -> bf16 ctx ----------------
__global__ __launch_bounds__(256) void attn_merge(
    const float* __restrict__ o0, const float* __restrict__ o1,
    const float* __restrict__ o2,
    const float* __restrict__ mlbuf, u16* __restrict__ ctx)
{
  int t = threadIdx.x;
  int R = blockIdx.x * 4 + (t >> 6);   // (b*cNH+h)*cS + q
  int d = t & 63;
  float ms[KSPLIT], ls[KSPLIT];
  float m = -1e30f;
  #pragma unroll
  for (int s = 0; s < KSPLIT; s++) {
    ms[s] = mlbuf[((size_t)s * NRB + R) * 2];
    ls[s] = mlbuf[((size_t)s * NRB + R) * 2 + 1];
    m = fmaxf(m, ms[s]);
  }
  const float* ops[KSPLIT] = {o0, o1, o2};
  float num = 0.f, den = 0.f;
  #pragma unroll
  for (int s = 0; s < KSPLIT; s++) {
    float a = exp2f(ms[s] - m);
    num += ops[s][(size_t)R * cHD + d] * a;
    den += ls[s] * a;
  }
  float val = num / den;
  int q = R & (cS - 1), h = (R >> 10) & 15, b = R >> 14;
  ctx[((size_t)b * cS + q) * cH + h * cHD + d] = f2u(val);
}

extern "C" void kernel_launch(void* const* d_in, const int* in_sizes, int n_in,
                              void* d_out, int out_size, void* d_ws, size_t ws_size,
                              hipStream_t stream)
{
  const float* hidden = (const float*)d_in[0];
  const float* cache  = (const float*)d_in[1];
  const float* ln_s   = (const float*)d_in[2];
  const float* ln_b   = (const float*)d_in[3];
  const float* Wq     = (const float*)d_in[4];
  const float* Wk     = (const float*)d_in[5];
  const float* Wv     = (const float*)d_in[6];
  const float* Wo     = (const float*)d_in[7];
  const float* gate   = (const float*)d_in[8];
  const float* lsc    = (const float*)d_in[9];
  float* outp = (float*)d_out;

  // ws: kvin 20.97M | vt 20.97M | opart(o0,o1) 16.78M | ropetab 0.26M  (~59.0 MB)
  u16* kvin = (u16*)d_ws;
  u16* vt   = kvin + (size_t)cB * cL * cH;
  float* opart = (float*)(vt + (size_t)cB * cL * cH);
  float* o0 = opart;
  float* o1 = opart + (size_t)cB * cNH * cS * cHD;          // +8.39MB
  float2* ropetab = (float2*)(o1 + (size_t)cB * cNH * cS * cHD);  // 256 KB
  // aliases into kvin (dead rows by the time these are written):
  u16* ctx = kvin + (size_t)2 * 1024 * 1024;      // [4.19M, 8.39M) written by attn_merge
  float* o2 = (float*)(kvin + (size_t)4 * 1024 * 1024);   // bytes [8.39M, 16.78M)
  float* mlbuf = (float*)(kvin + (size_t)8 * 1024 * 1024);// bytes [16.78M, 17.57M)
  // scratch parked in d_out (overwritten by memcpy/final-LN at the end):
  u16* kb = (u16*)(outp + (size_t)cB * cS * cH);          // [8.39M, 29.36M)
  u16* qb = (u16*)(outp + (size_t)7 * cB * cS * cH / 2);  // [29.36M, 33.55M) exact fit
  u16* Wt = (u16*)(outp + (size_t)(1 + 3) * cB * cS * cH);// [33.55M, 41.94M)
  u16* Wt_o = Wt + (size_t)3 * cH * cH;

  // 1) prep: weight transpose + cache->kvin + pre-norm + RoPE table, one launch
  prep<<<14464, 256, 0, stream>>>(Wq, Wk, Wv, Wo, Wt, cache, kvin,
                                  hidden, ln_s, ln_b, ropetab);

  // 2) merged K|V + Q projections (mode 6; RoPE via table in mode-1 epilogues)
  mgemm<<<1408, 256, 0, stream>>>(
      kvin, Wt, 0, 0, 0, 0, 6, kb, vt, qb, (const float2*)ropetab,
      nullptr, nullptr, nullptr, nullptr, nullptr);

  // 3) 3-way split-K MFMA flash attention (2 q-tiles/wave) -> partials -> merge
  attn_mfma<<<dim3(cS / 128, cNH, cB * KSPLIT), 256, 0, stream>>>(
      qb, kb, vt, o0, o1, o2, mlbuf);
  attn_merge<<<(cB * cNH * cS) / 4, 256, 0, stream>>>(o0, o1, o2, mlbuf, ctx);

  // 4) ctx @ Wo with fused gated residual -> output f32
  mgemm<<<dim3(8, (cB * cS) / GBM), 256, 0, stream>>>(
      ctx, Wt_o, cB * cS, 0, cB * cS, cB * cS, 2, nullptr, nullptr, nullptr,
      nullptr, hidden, cache, gate, lsc, outp);

  // 5) new_cache[0:3] = cache[1:4]  (overwrites kb+qb scratch — both dead)
  hipMemcpyAsync(outp + (size_t)cB * cS * cH, cache + (size_t)cB * cS * cH,
                 (size_t)(cW - 1) * cB * cS * cH * sizeof(float),
                 hipMemcpyDeviceToDevice, stream);
  // 6) final layernorm -> new_cache slot 3 (overwrites Wt scratch)
  ln_f32<<<cB * cS, 256, 0, stream>>>(outp, outp + (size_t)cW * cB * cS * cH, ln_s, ln_b);
}